// Round 8
// baseline (466.447 us; speedup 1.0000x reference)
//
#include <hip/hip_runtime.h>

typedef unsigned short u16;
typedef short short8 __attribute__((ext_vector_type(8)));
typedef float floatx4 __attribute__((ext_vector_type(4)));

#define B_  2
#define L_  2048
#define D_  1024
#define H_  16
#define HD_ 64
#define M_  (B_*L_)      // 4096 rows
#define LP_ 1024         // compressed (per-parity) seq len
#define WP_ 256          // compressed window

__device__ __forceinline__ float b2f(u16 u) {
    union { unsigned int i; float f; } c; c.i = ((unsigned int)u) << 16; return c.f;
}
__device__ __forceinline__ u16 f2b(float f) {
    union { float f; unsigned int i; } c; c.f = f;
    unsigned int u = c.i;
    u = u + 0x7FFFu + ((u >> 16) & 1u);   // RNE
    return (u16)(u >> 16);
}
__device__ __forceinline__ float ldrawf(const void* p, size_t i, bool isbf16) {
    return isbf16 ? b2f(((const u16*)p)[i]) : ((const float*)p)[i];
}
__device__ __forceinline__ u16 ldraw16(const void* p, size_t i, bool isbf16) {
    return isbf16 ? ((const u16*)p)[i] : f2b(((const float*)p)[i]);
}
// cheap GELU (tanh form), max dev from erf form ~1e-3
__device__ __forceinline__ float gelu_f(float x) {
    float x3 = x * x * x;
    float y2 = 1.5957691216057308f * (x + 0.044715f * x3);
    float e  = __expf(y2);
    float th = 1.0f - 2.0f / (e + 1.0f);
    return 0.5f * x * (1.0f + th);
}
// async global->LDS, 16B per lane (LDS dst must be wave-base + lane*16)
__device__ __forceinline__ void gload16(const u16* g, u16* l) {
    __builtin_amdgcn_global_load_lds(
        (__attribute__((address_space(1))) void*)(g),
        (__attribute__((address_space(3))) void*)(l), 16, 0, 0);
}

// ---------------- dtype probe ----------------
__global__ void probe_k(const u16* x, int* flag) {
    int t = threadIdx.x;
    unsigned int u = x[2 * t];
    unsigned int e = (u >> 7) & 0xFF;
    bool sane = (e >= 100 && e <= 140);
    unsigned long long m = __ballot(sane);
    if (t == 0) *flag = (__popcll(m) >= 32) ? 1 : 0;   // 1 = bf16 inputs
}

// ---------------- merged weight transpose: 4 matrices, one launch ----------------
__device__ __forceinline__ void tr_body(const void* in, u16* out, int K, int N,
                                        int bx, int by, bool isb) {
    __shared__ u16 tile[32][33];
    int tx = threadIdx.x & 31;
    int ty = threadIdx.x >> 5;
    int nb = bx * 32, kb = by * 32;
    #pragma unroll
    for (int j = 0; j < 32; j += 8)
        tile[ty + j][tx] = ldraw16(in, (size_t)(kb + ty + j) * N + nb + tx, isb);
    __syncthreads();
    #pragma unroll
    for (int j = 0; j < 32; j += 8)
        out[(size_t)(nb + ty + j) * K + kb + tx] = tile[tx][ty + j];
}
__global__ __launch_bounds__(256) void transpose_all_k(
        const void* w0, const void* w1, const void* w2, const void* w3,
        u16* o0, u16* o1, u16* o2, u16* o3, const int* flagp) {
    bool isb = (*flagp != 0);
    int id = blockIdx.x;
    if (id < 3072)            { int l = id;         tr_body(w0, o0, 1024, 3072, l % 96,  l / 96,  isb); }
    else if (id < 4096)       { int l = id - 3072;  tr_body(w1, o1, 1024, 1024, l % 32,  l / 32,  isb); }
    else if (id < 8192)       { int l = id - 4096;  tr_body(w2, o2, 1024, 4096, l % 128, l / 128, isb); }
    else                      { int l = id - 8192;  tr_body(w3, o3, 4096, 1024, l % 32,  l / 32,  isb); }
}

// ---------------- LayerNorm ----------------
template<int SRC>
__global__ __launch_bounds__(256) void ln_k(const void* __restrict__ x, const void* __restrict__ g,
                                            const void* __restrict__ bb, u16* __restrict__ out,
                                            const int* flagp) {
    bool isb = (*flagp != 0);
    int row = blockIdx.x;
    int t = threadIdx.x;
    float v[4]; float s = 0.f, s2 = 0.f;
    #pragma unroll
    for (int i = 0; i < 4; i++) {
        size_t idx = (size_t)row * D_ + t + 256 * i;
        float f = (SRC == 1) ? ((const float*)x)[idx] : ldrawf(x, idx, isb);
        v[i] = f; s += f; s2 += f * f;
    }
    #pragma unroll
    for (int off = 32; off >= 1; off >>= 1) { s += __shfl_xor(s, off); s2 += __shfl_xor(s2, off); }
    __shared__ float red[8];
    int wave = t >> 6;
    if ((t & 63) == 0) { red[wave] = s; red[4 + wave] = s2; }
    __syncthreads();
    s  = red[0] + red[1] + red[2] + red[3];
    s2 = red[4] + red[5] + red[6] + red[7];
    float mu  = s * (1.0f / 1024.0f);
    float var = s2 * (1.0f / 1024.0f) - mu * mu;
    float rs  = rsqrtf(var + 1e-5f);
    #pragma unroll
    for (int i = 0; i < 4; i++) {
        int c = t + 256 * i;
        out[(size_t)row * D_ + c] = f2b((v[i] - mu) * rs * ldrawf(g, c, isb) + ldrawf(bb, c, isb));
    }
}

// ---------------- 2-wave high-ILP GEMM: 128x128 tile, wave = 64x128 (4m x 8n) ----------------
// 128 threads. Per wave per BK=32: 12 ds_read_b128, 32 indep MFMAs. dbuf + gload16.
// out bf16 ws, +bias, optional GELU.
template<int GELU>
__global__ __launch_bounds__(128) void gemm2w_k(const u16* __restrict__ A,
                                                const u16* __restrict__ BT,
                                                const void* __restrict__ bias,
                                                u16* __restrict__ C,
                                                int M, int N, int K,
                                                const int* flagp) {
    __shared__ __align__(16) u16 a_s[2][128 * 32];
    __shared__ __align__(16) u16 b_s[2][128 * 32];
    bool isb = (*flagp != 0);

    const int bm = blockIdx.y, bn = blockIdx.x;
    const int t = threadIdx.x, w = t >> 6, lane = t & 63;
    const int quad = lane >> 4, r16 = lane & 15;
    const int nIter = K / 32;

    const int lr  = lane >> 2;
    const int lcg = (((lane & 3) ^ ((lr >> 1) & 3))) * 8;
    const u16* Ag[4]; const u16* Bg[4]; int aloff[4], bloff[4];
    #pragma unroll
    for (int j = 0; j < 4; j++) {
        Ag[j] = A  + (size_t)(bm * 128 + w * 64 + j * 16 + lr) * K + lcg;
        Bg[j] = BT + (size_t)(bn * 128 + w * 64 + j * 16 + lr) * K + lcg;
        aloff[j] = (w * 64 + j * 16 + lr) * 32 + (lane & 3) * 8;
        bloff[j] = aloff[j];
    }
    const int sw = ((r16 >> 1) & 3);
    floatx4 acc[4][8] = {};

    #pragma unroll
    for (int j = 0; j < 4; j++) { gload16(Ag[j], a_s[0] + aloff[j]); gload16(Bg[j], b_s[0] + bloff[j]); }

    for (int i = 0; i < nIter; i++) {
        const int cur = i & 1, nxt = cur ^ 1;
        __syncthreads();
        if (i + 1 < nIter) {
            int kc = (i + 1) * 32;
            #pragma unroll
            for (int j = 0; j < 4; j++) {
                gload16(Ag[j] + kc, a_s[nxt] + aloff[j]);
                gload16(Bg[j] + kc, b_s[nxt] + bloff[j]);
            }
        }
        short8 af[4], bf[8];
        #pragma unroll
        for (int mt = 0; mt < 4; mt++)
            af[mt] = *(const short8*)(a_s[cur] + (w * 64 + mt * 16 + r16) * 32 + (quad ^ sw) * 8);
        #pragma unroll
        for (int nt = 0; nt < 8; nt++)
            bf[nt] = *(const short8*)(b_s[cur] + (nt * 16 + r16) * 32 + (quad ^ sw) * 8);
        #pragma unroll
        for (int mt = 0; mt < 4; mt++)
            #pragma unroll
            for (int nt = 0; nt < 8; nt++)
                acc[mt][nt] = __builtin_amdgcn_mfma_f32_16x16x32_bf16(af[mt], bf[nt], acc[mt][nt], 0, 0, 0);
    }

    #pragma unroll
    for (int mt = 0; mt < 4; mt++)
      #pragma unroll
      for (int nt = 0; nt < 8; nt++)
        #pragma unroll
        for (int r = 0; r < 4; r++) {
            int row = bm * 128 + w * 64 + mt * 16 + quad * 4 + r;
            int col = bn * 128 + nt * 16 + r16;
            float v = acc[mt][nt][r] + ldrawf(bias, col, isb);
            if (GELU) v = gelu_f(v);
            C[(size_t)row * N + col] = f2b(v);
        }
}

// ---------------- 4-wave GEMM (m97 structure) for narrow-N shapes ----------------
// OUT: 0 fp32 ws, 3 bf16 split-K partial. RES: 1 raw input resid. SPLITK via blockIdx.z.
template<int NT, int OUT, int RES, int SPLITK>
__global__ __launch_bounds__(256) void gemm128_k(const u16* __restrict__ A,
                                                 const u16* __restrict__ BT,
                                                 const void* __restrict__ bias,
                                                 const void* __restrict__ resid,
                                                 void* __restrict__ C,
                                                 int M, int N, int K,
                                                 const int* flagp) {
    constexpr int TN = NT * 32;
    __shared__ __align__(16) u16 a_s[2][128 * 32];
    __shared__ __align__(16) u16 b_s[2][TN * 32];
    bool isb = (*flagp != 0);

    const int bm = blockIdx.y, bn = blockIdx.x;
    const int kz = (SPLITK > 1) ? blockIdx.z : 0;
    const int Kc = K / SPLITK;
    const int k_beg = kz * Kc;
    const int nIter = Kc / 32;

    const int t = threadIdx.x, w = t >> 6, lane = t & 63;
    const int wm = w >> 1, wn = w & 1;
    const int quad = lane >> 4, r16 = lane & 15;

    const int lr  = lane >> 2;
    const int lcg = (((lane & 3) ^ ((lr >> 1) & 3))) * 8;
    const u16* Ag0 = A  + (size_t)(bm * 128 + w * 32 + lr) * K + lcg + k_beg;
    const u16* Ag1 = Ag0 + (size_t)16 * K;
    const u16* Bg0 = BT + (size_t)(bn * TN + w * (TN / 4) + lr) * K + lcg + k_beg;
    const u16* Bg1 = Bg0 + (size_t)16 * K;
    const int aoff0 = (w * 32 + lr) * 32 + (lane & 3) * 8;
    const int aoff1 = aoff0 + 16 * 32;
    const int boff0 = (w * (TN / 4) + lr) * 32 + (lane & 3) * 8;
    const int boff1 = boff0 + 16 * 32;

    const int sw = ((r16 >> 1) & 3);
    floatx4 acc[4][NT] = {};

    gload16(Ag0, a_s[0] + aoff0);
    gload16(Ag1, a_s[0] + aoff1);
    gload16(Bg0, b_s[0] + boff0);
    if constexpr (NT == 4) gload16(Bg1, b_s[0] + boff1);

    for (int i = 0; i < nIter; i++) {
        const int cur = i & 1, nxt = cur ^ 1;
        __syncthreads();
        if (i + 1 < nIter) {
            int kc2 = (i + 1) * 32;
            gload16(Ag0 + kc2, a_s[nxt] + aoff0);
            gload16(Ag1 + kc2, a_s[nxt] + aoff1);
            gload16(Bg0 + kc2, b_s[nxt] + boff0);
            if constexpr (NT == 4) gload16(Bg1 + kc2, b_s[nxt] + boff1);
        }
        short8 af[4], bf[NT];
        #pragma unroll
        for (int mt = 0; mt < 4; mt++)
            af[mt] = *(const short8*)(a_s[cur] + (wm * 64 + mt * 16 + r16) * 32 + (quad ^ sw) * 8);
        #pragma unroll
        for (int nt = 0; nt < NT; nt++)
            bf[nt] = *(const short8*)(b_s[cur] + (wn * (TN / 2) + nt * 16 + r16) * 32 + (quad ^ sw) * 8);
        #pragma unroll
        for (int mt = 0; mt < 4; mt++)
            #pragma unroll
            for (int nt = 0; nt < NT; nt++)
                acc[mt][nt] = __builtin_amdgcn_mfma_f32_16x16x32_bf16(af[mt], bf[nt], acc[mt][nt], 0, 0, 0);
    }

    #pragma unroll
    for (int mt = 0; mt < 4; mt++)
      #pragma unroll
      for (int nt = 0; nt < NT; nt++)
        #pragma unroll
        for (int r = 0; r < 4; r++) {
            int row = bm * 128 + wm * 64 + mt * 16 + quad * 4 + r;
            int col = bn * TN + wn * (TN / 2) + nt * 16 + r16;
            size_t oi = (size_t)row * N + col;
            if (OUT == 3) {
                ((u16*)C)[(size_t)kz * M * N + oi] = f2b(acc[mt][nt][r]);
            } else {
                float v = acc[mt][nt][r] + ldrawf(bias, col, isb);
                if (RES == 1) v += ldrawf(resid, (size_t)row * N + col, isb);
                ((float*)C)[oi] = v;
            }
        }
}

// ---------------- split-K reduce: out = x1 + b2 + sum_z part[z] ----------------
__global__ __launch_bounds__(256) void reduce_k(const u16* __restrict__ part,
                                                const float* __restrict__ x1,
                                                const void* __restrict__ b2,
                                                void* __restrict__ out,
                                                const int* flagp) {
    bool isb = (*flagp != 0);
    size_t i0 = ((size_t)blockIdx.x * 256 + threadIdx.x) * 4;
    float4 xv = *(const float4*)(x1 + i0);
    float r[4] = { xv.x, xv.y, xv.z, xv.w };
    #pragma unroll
    for (int j = 0; j < 4; j++) r[j] += ldrawf(b2, (i0 + j) & (D_ - 1), isb);
    #pragma unroll
    for (int z = 0; z < 4; z++) {
        ushort4 pv = *(const ushort4*)(part + (size_t)z * M_ * D_ + i0);
        r[0] += b2f(pv.x); r[1] += b2f(pv.y); r[2] += b2f(pv.z); r[3] += b2f(pv.w);
    }
    if (isb) {
        ushort4 ov = { f2b(r[0]), f2b(r[1]), f2b(r[2]), f2b(r[3]) };
        *(ushort4*)((u16*)out + i0) = ov;
    } else {
        float4 ov = { r[0], r[1], r[2], r[3] };
        *(float4*)((float*)out + i0) = ov;
    }
}

// ---------------- repack V only: qkv v-cols -> Vt [pid][64][l'] ----------------
__global__ __launch_bounds__(256) void repack_v_k(const u16* __restrict__ qkv,
                                                  u16* __restrict__ Vt) {
    int pid = blockIdx.x;            // 0..63
    int lt  = blockIdx.y;            // 0..15
    int b = pid >> 5, p = (pid >> 4) & 1, h = pid & 15;
    int t = threadIdx.x;
    int srow = t >> 2;
    int scol = (t & 3) * 16;

    int lp = lt * 64 + srow;
    int l  = 2 * lp + p;
    const u16* src = qkv + ((size_t)b * L_ + l) * (3 * D_) + 2 * D_ + h * HD_;

    __shared__ u16 vt[64][72];
    *(int4*)(&vt[srow][scol])     = *(const int4*)(src + scol);
    *(int4*)(&vt[srow][scol + 8]) = *(const int4*)(src + scol + 8);
    __syncthreads();
    union { u16 s[16]; int4 v[2]; } tmp;
    #pragma unroll
    for (int jj = 0; jj < 16; jj++) tmp.s[jj] = vt[scol + jj][srow];
    u16* vdst = Vt + ((size_t)pid * HD_ + srow) * LP_ + lt * 64 + scol;
    *(int4*)(vdst)     = tmp.v[0];
    *(int4*)(vdst + 8) = tmp.v[1];
}

// ---------------- flash attention (parity-compressed), reg-prefetch K/V ----------------
#define FS 72
__global__ __launch_bounds__(256) void fattn_k(const u16* __restrict__ qkv,
                                               const u16* __restrict__ Vt,
                                               u16* __restrict__ o) {
    __shared__ __align__(16) u16 Qs[64 * FS];
    __shared__ __align__(16) u16 Ks[64 * FS];
    __shared__ __align__(16) u16 Vs[64 * FS];
    __shared__ __align__(16) u16 Ps[4][16 * FS];

    const int pid = blockIdx.x, qt = blockIdx.y;
    const int b = pid >> 5, p = (pid >> 4) & 1, h = pid & 15;
    const int t = threadIdx.x, w = t >> 6, lane = t & 63;
    const int quad = lane >> 4, r16 = lane & 15;
    const int q0 = qt * 64;

    const int srow = t >> 2;
    const int scol = (t & 3) * 16;

    // stage Q tile from qkv (l = 2*(q0+srow)+p)
    const u16* qsrc = qkv + ((size_t)b * L_ + 2 * (q0 + srow) + p) * (3 * D_) + h * HD_;
    *(int4*)(Qs + srow * FS + scol)     = *(const int4*)(qsrc + scol);
    *(int4*)(Qs + srow * FS + scol + 8) = *(const int4*)(qsrc + scol + 8);
    __syncthreads();

    const short8 qf0 = *(const short8*)(Qs + (w * 16 + r16) * FS + quad * 8);
    const short8 qf1 = *(const short8*)(Qs + (w * 16 + r16) * FS + quad * 8 + 32);

    floatx4 oacc[4] = {};
    float mrow[4] = {-INFINITY, -INFINITY, -INFINITY, -INFINITY};
    float lrow[4] = {};

    const int kt0 = (qt >= 4) ? qt - 4 : 0;
    const int qrow_base = q0 + w * 16 + quad * 4;

    // register prefetch for kt0
    auto kaddr = [&](int kt) {
        return qkv + ((size_t)b * L_ + 2 * (kt * 64 + srow) + p) * (3 * D_) + D_ + h * HD_;
    };
    auto vaddr = [&](int kt) {
        return Vt + ((size_t)pid * HD_ + srow) * LP_ + kt * 64;
    };
    int4 kr0 = *(const int4*)(kaddr(kt0) + scol);
    int4 kr1 = *(const int4*)(kaddr(kt0) + scol + 8);
    int4 vr0 = *(const int4*)(vaddr(kt0) + scol);
    int4 vr1 = *(const int4*)(vaddr(kt0) + scol + 8);

    for (int kt = kt0; kt <= qt; ++kt) {
        __syncthreads();
        *(int4*)(Ks + srow * FS + scol)     = kr0;
        *(int4*)(Ks + srow * FS + scol + 8) = kr1;
        *(int4*)(Vs + srow * FS + scol)     = vr0;
        *(int4*)(Vs + srow * FS + scol + 8) = vr1;
        __syncthreads();
        if (kt < qt) {   // prefetch next tile; vmcnt waited at next iter's stores
            kr0 = *(const int4*)(kaddr(kt + 1) + scol);
            kr1 = *(const int4*)(kaddr(kt + 1) + scol + 8);
            vr0 = *(const int4*)(vaddr(kt + 1) + scol);
            vr1 = *(const int4*)(vaddr(kt + 1) + scol + 8);
        }

        floatx4 s4[4];
        #pragma unroll
        for (int nt = 0; nt < 4; nt++) {
            short8 kf0 = *(const short8*)(Ks + (nt * 16 + r16) * FS + quad * 8);
            short8 kf1 = *(const short8*)(Ks + (nt * 16 + r16) * FS + quad * 8 + 32);
            floatx4 z = {};
            z = __builtin_amdgcn_mfma_f32_16x16x32_bf16(qf0, kf0, z, 0, 0, 0);
            z = __builtin_amdgcn_mfma_f32_16x16x32_bf16(qf1, kf1, z, 0, 0, 0);
            s4[nt] = z;
        }

        float sv[4][4];
        #pragma unroll
        for (int nt = 0; nt < 4; nt++) {
            int kcol = kt * 64 + nt * 16 + r16;
            #pragma unroll
            for (int r = 0; r < 4; r++) {
                int kq = kcol - (qrow_base + r);
                bool valid = (kq <= 0) && (kq >= -WP_);
                sv[nt][r] = valid ? s4[nt][r] * 0.125f : -1e30f;
            }
        }

        float mx[4];
        #pragma unroll
        for (int r = 0; r < 4; r++)
            mx[r] = fmaxf(fmaxf(sv[0][r], sv[1][r]), fmaxf(sv[2][r], sv[3][r]));
        #pragma unroll
        for (int off = 8; off >= 1; off >>= 1)
            #pragma unroll
            for (int r = 0; r < 4; r++) mx[r] = fmaxf(mx[r], __shfl_xor(mx[r], off));

        float al[4];
        #pragma unroll
        for (int r = 0; r < 4; r++) {
            float mnew = fmaxf(mrow[r], mx[r]);
            al[r] = __expf(mrow[r] - mnew);
            mrow[r] = mnew;
        }

        float ps[4][4], rs[4] = {};
        #pragma unroll
        for (int nt = 0; nt < 4; nt++)
            #pragma unroll
            for (int r = 0; r < 4; r++) {
                float pv = __expf(sv[nt][r] - mrow[r]);
                ps[nt][r] = pv; rs[r] += pv;
            }
        #pragma unroll
        for (int off = 8; off >= 1; off >>= 1)
            #pragma unroll
            for (int r = 0; r < 4; r++) rs[r] += __shfl_xor(rs[r], off);
        #pragma unroll
        for (int r = 0; r < 4; r++) lrow[r] = lrow[r] * al[r] + rs[r];
        #pragma unroll
        for (int nt = 0; nt < 4; nt++)
            #pragma unroll
            for (int r = 0; r < 4; r++) oacc[nt][r] *= al[r];

        #pragma unroll
        for (int nt = 0; nt < 4; nt++)
            #pragma unroll
            for (int r = 0; r < 4; r++)
                Ps[w][(quad * 4 + r) * FS + nt * 16 + r16] = f2b(ps[nt][r]);
        short8 pf0 = *(const short8*)(&Ps[w][r16 * FS + quad * 8]);
        short8 pf1 = *(const short8*)(&Ps[w][r16 * FS + quad * 8 + 32]);

        #pragma unroll
        for (int nt = 0; nt < 4; nt++) {
            short8 vf0 = *(const short8*)(Vs + (nt * 16 + r16) * FS + quad * 8);
            short8 vf1 = *(const short8*)(Vs + (nt * 16 + r16) * FS + quad * 8 + 32);
            oacc[nt] = __builtin_amdgcn_mfma_f32_16x16x32_bf16(pf0, vf0, oacc[nt], 0, 0, 0);
            oacc[nt] = __builtin_amdgcn_mfma_f32_16x16x32_bf16(pf1, vf1, oacc[nt], 0, 0, 0);
        }
    }

    float inv[4];
    #pragma unroll
    for (int r = 0; r < 4; r++) inv[r] = 1.0f / lrow[r];
    #pragma unroll
    for (int nt = 0; nt < 4; nt++)
        #pragma unroll
        for (int r = 0; r < 4; r++) {
            int qp = qrow_base + r;
            int l  = 2 * qp + p;
            int d  = nt * 16 + r16;
            o[((size_t)b * L_ + l) * D_ + h * HD_ + d] = f2b(oacc[nt][r] * inv[r]);
        }
}

// ---------------- orchestration ----------------
extern "C" void kernel_launch(void* const* d_in, const int* in_sizes, int n_in,
                              void* d_out, int out_size, void* d_ws, size_t ws_size,
                              hipStream_t stream) {
    (void)in_sizes; (void)n_in; (void)out_size; (void)ws_size;
    const void* x     = d_in[0];
    const void* ln1_g = d_in[1];
    const void* ln1_b = d_in[2];
    const void* Wqkv  = d_in[3];
    const void* bqkv  = d_in[4];
    const void* Wout  = d_in[5];
    const void* bout  = d_in[6];
    const void* ln2_g = d_in[7];
    const void* ln2_b = d_in[8];
    const void* W1    = d_in[9];
    const void* b1    = d_in[10];
    const void* W2    = d_in[11];
    const void* b2    = d_in[12];

    char* ws = (char*)d_ws;
    const size_t MB = 1024 * 1024;
    u16*   wqkvT = (u16*)ws;                      // 6MB   [3D, D]
    u16*   qkv   = (u16*)(ws + 6  * MB);          // 24MB  [M, 3D]
    u16*   woutT = (u16*)(ws + 30 * MB);          // 2MB   [D, D]
    u16*   fbuf  = (u16*)ws;                      // 32MB  [M,4D] overlay (GEMM3+)
    u16*   w1T   = (u16*)(ws + 32 * MB);          // 8MB   [4D, D]
    u16*   w2T   = (u16*)(ws + 40 * MB);          // 8MB   [D, 4D]
    u16*   bufA  = (u16*)(ws + 48 * MB);          // 8MB   [M, D]
    float* x1    = (float*)(ws + 56 * MB);        // 16MB  [M, D] f32
    u16*   Vt    = (u16*)(ws + 72 * MB);          // 8MB   [64][64][1024]
    u16*   part  = (u16*)(ws + 80 * MB);          // 32MB  4 x [M, D] bf16 split-K partials
    int*   flag  = (int*)(ws + 112 * MB);

    dim3 tb(256);
    probe_k<<<1, 64, 0, stream>>>((const u16*)x, flag);

    transpose_all_k<<<12288, tb, 0, stream>>>(Wqkv, Wout, W1, W2, wqkvT, woutT, w1T, w2T, flag);

    ln_k<0><<<M_, tb, 0, stream>>>(x, ln1_g, ln1_b, bufA, flag);

    // GEMM1: qkv = h @ Wqkv + bqkv    [4096 x 3072 x 1024], 2-wave 128x128
    gemm2w_k<0><<<dim3(3 * D_ / 128, M_ / 128), dim3(128), 0, stream>>>(bufA, wqkvT, bqkv, qkv, M_, 3 * D_, D_, flag);

    repack_v_k<<<dim3(64, 16), tb, 0, stream>>>(qkv, Vt);
    fattn_k<<<dim3(64, 16), tb, 0, stream>>>(qkv, Vt, bufA);

    // GEMM2: x1 = o @ Wout + bout + x  [4096 x 1024 x 1024], 4-wave 128x64
    gemm128_k<2, 0, 1, 1><<<dim3(D_ / 64, M_ / 128), tb, 0, stream>>>(bufA, woutT, bout, x, x1, M_, D_, D_, flag);

    ln_k<1><<<M_, tb, 0, stream>>>(x1, ln2_g, ln2_b, bufA, flag);

    // GEMM3: f = gelu(h2 @ W1 + b1)   [4096 x 4096 x 1024], 2-wave 128x128
    gemm2w_k<1><<<dim3(4 * D_ / 128, M_ / 128), dim3(128), 0, stream>>>(bufA, w1T, b1, fbuf, M_, 4 * D_, D_, flag);

    // GEMM4 split-K=4: part[z] = f @ W2 (K-chunk z)  [4096 x 1024 x 4096]
    gemm128_k<2, 3, 0, 4><<<dim3(D_ / 64, M_ / 128, 4), tb, 0, stream>>>(fbuf, w2T, nullptr, nullptr, part, M_, D_, 4 * D_, flag);
    reduce_k<<<(M_ * D_) / 1024, tb, 0, stream>>>(part, x1, b2, d_out, flag);
}

// Round 9
// 391.012 us; speedup vs baseline: 1.1929x; 1.1929x over previous
//
#include <hip/hip_runtime.h>

typedef unsigned short u16;
typedef short short8 __attribute__((ext_vector_type(8)));
typedef float floatx4 __attribute__((ext_vector_type(4)));

#define B_  2
#define L_  2048
#define D_  1024
#define H_  16
#define HD_ 64
#define M_  (B_*L_)      // 4096 rows
#define LP_ 1024         // compressed (per-parity) seq len
#define WP_ 256          // compressed window

__device__ __forceinline__ float b2f(u16 u) {
    union { unsigned int i; float f; } c; c.i = ((unsigned int)u) << 16; return c.f;
}
__device__ __forceinline__ u16 f2b(float f) {
    union { float f; unsigned int i; } c; c.f = f;
    unsigned int u = c.i;
    u = u + 0x7FFFu + ((u >> 16) & 1u);   // RNE
    return (u16)(u >> 16);
}
__device__ __forceinline__ float ldrawf(const void* p, size_t i, bool isbf16) {
    return isbf16 ? b2f(((const u16*)p)[i]) : ((const float*)p)[i];
}
__device__ __forceinline__ u16 ldraw16(const void* p, size_t i, bool isbf16) {
    return isbf16 ? ((const u16*)p)[i] : f2b(((const float*)p)[i]);
}
// cheap GELU (tanh form), max dev from erf form ~1e-3
__device__ __forceinline__ float gelu_f(float x) {
    float x3 = x * x * x;
    float y2 = 1.5957691216057308f * (x + 0.044715f * x3);
    float e  = __expf(y2);
    float th = 1.0f - 2.0f / (e + 1.0f);
    return 0.5f * x * (1.0f + th);
}
// async global->LDS, 16B per lane (LDS dst must be wave-base + lane*16)
__device__ __forceinline__ void gload16(const u16* g, u16* l) {
    __builtin_amdgcn_global_load_lds(
        (__attribute__((address_space(1))) void*)(g),
        (__attribute__((address_space(3))) void*)(l), 16, 0, 0);
}

// ---------------- dtype probe ----------------
__global__ void probe_k(const u16* x, int* flag) {
    int t = threadIdx.x;
    unsigned int u = x[2 * t];
    unsigned int e = (u >> 7) & 0xFF;
    bool sane = (e >= 100 && e <= 140);
    unsigned long long m = __ballot(sane);
    if (t == 0) *flag = (__popcll(m) >= 32) ? 1 : 0;   // 1 = bf16 inputs
}

// ---------------- merged weight transpose: 4 matrices, one launch ----------------
__device__ __forceinline__ void tr_body(const void* in, u16* out, int K, int N,
                                        int bx, int by, bool isb) {
    __shared__ u16 tile[32][33];
    int tx = threadIdx.x & 31;
    int ty = threadIdx.x >> 5;
    int nb = bx * 32, kb = by * 32;
    #pragma unroll
    for (int j = 0; j < 32; j += 8)
        tile[ty + j][tx] = ldraw16(in, (size_t)(kb + ty + j) * N + nb + tx, isb);
    __syncthreads();
    #pragma unroll
    for (int j = 0; j < 32; j += 8)
        out[(size_t)(nb + ty + j) * K + kb + tx] = tile[tx][ty + j];
}
__global__ __launch_bounds__(256) void transpose_all_k(
        const void* w0, const void* w1, const void* w2, const void* w3,
        u16* o0, u16* o1, u16* o2, u16* o3, const int* flagp) {
    bool isb = (*flagp != 0);
    int id = blockIdx.x;
    if (id < 3072)            { int l = id;         tr_body(w0, o0, 1024, 3072, l % 96,  l / 96,  isb); }
    else if (id < 4096)       { int l = id - 3072;  tr_body(w1, o1, 1024, 1024, l % 32,  l / 32,  isb); }
    else if (id < 8192)       { int l = id - 4096;  tr_body(w2, o2, 1024, 4096, l % 128, l / 128, isb); }
    else                      { int l = id - 8192;  tr_body(w3, o3, 4096, 1024, l % 32,  l / 32,  isb); }
}

// ---------------- LayerNorm ----------------
template<int SRC>
__global__ __launch_bounds__(256) void ln_k(const void* __restrict__ x, const void* __restrict__ g,
                                            const void* __restrict__ bb, u16* __restrict__ out,
                                            const int* flagp) {
    bool isb = (*flagp != 0);
    int row = blockIdx.x;
    int t = threadIdx.x;
    float v[4]; float s = 0.f, s2 = 0.f;
    #pragma unroll
    for (int i = 0; i < 4; i++) {
        size_t idx = (size_t)row * D_ + t + 256 * i;
        float f = (SRC == 1) ? ((const float*)x)[idx] : ldrawf(x, idx, isb);
        v[i] = f; s += f; s2 += f * f;
    }
    #pragma unroll
    for (int off = 32; off >= 1; off >>= 1) { s += __shfl_xor(s, off); s2 += __shfl_xor(s2, off); }
    __shared__ float red[8];
    int wave = t >> 6;
    if ((t & 63) == 0) { red[wave] = s; red[4 + wave] = s2; }
    __syncthreads();
    s  = red[0] + red[1] + red[2] + red[3];
    s2 = red[4] + red[5] + red[6] + red[7];
    float mu  = s * (1.0f / 1024.0f);
    float var = s2 * (1.0f / 1024.0f) - mu * mu;
    float rs  = rsqrtf(var + 1e-5f);
    #pragma unroll
    for (int i = 0; i < 4; i++) {
        int c = t + 256 * i;
        out[(size_t)row * D_ + c] = f2b((v[i] - mu) * rs * ldrawf(g, c, isb) + ldrawf(bb, c, isb));
    }
}

// ---------------- 4-wave dbuf MFMA GEMM: C[M,N] = A[M,K] @ BT[N,K]^T ----------------
// 128x(NT*32) tile, BK=32, 4 waves 2x2, wave = 4xNT accs of 16x16x32.
// Single-barrier dbuf K-loop; gload16 staging; XOR k-chunk swizzle (0 conflicts, r5).
// OUT: 0 fp32 ws, 1 bf16 ws, 3 bf16 split-K partial. RES: 0 none, 1 raw input.
template<int NT, int OUT, int RES, int GELU, int SPLITK>
__global__ __launch_bounds__(256) void gemm128_k(const u16* __restrict__ A,
                                                 const u16* __restrict__ BT,
                                                 const void* __restrict__ bias,
                                                 const void* __restrict__ resid,
                                                 void* __restrict__ C,
                                                 int M, int N, int K,
                                                 const int* flagp) {
    constexpr int TN = NT * 32;
    __shared__ __align__(16) u16 a_s[2][128 * 32];
    __shared__ __align__(16) u16 b_s[2][TN * 32];
    bool isb = (*flagp != 0);

    const int bm = blockIdx.y, bn = blockIdx.x;
    const int kz = (SPLITK > 1) ? blockIdx.z : 0;
    const int Kc = K / SPLITK;
    const int k_beg = kz * Kc;
    const int nIter = Kc / 32;

    const int t = threadIdx.x, w = t >> 6, lane = t & 63;
    const int wm = w >> 1, wn = w & 1;
    const int quad = lane >> 4, r16 = lane & 15;

    const int lr  = lane >> 2;
    const int lcg = (((lane & 3) ^ ((lr >> 1) & 3))) * 8;
    const u16* Ag0 = A  + (size_t)(bm * 128 + w * 32 + lr) * K + lcg + k_beg;
    const u16* Ag1 = Ag0 + (size_t)16 * K;
    const u16* Bg0 = BT + (size_t)(bn * TN + w * (TN / 4) + lr) * K + lcg + k_beg;
    const u16* Bg1 = Bg0 + (size_t)16 * K;
    const int aoff0 = (w * 32 + lr) * 32 + (lane & 3) * 8;
    const int aoff1 = aoff0 + 16 * 32;
    const int boff0 = (w * (TN / 4) + lr) * 32 + (lane & 3) * 8;
    const int boff1 = boff0 + 16 * 32;

    const int sw = ((r16 >> 1) & 3);
    floatx4 acc[4][NT] = {};

    gload16(Ag0, a_s[0] + aoff0);
    gload16(Ag1, a_s[0] + aoff1);
    gload16(Bg0, b_s[0] + boff0);
    if constexpr (NT == 4) gload16(Bg1, b_s[0] + boff1);

    for (int i = 0; i < nIter; i++) {
        const int cur = i & 1, nxt = cur ^ 1;
        __syncthreads();   // drains cur-tile loads (issued one compute phase ago)
        if (i + 1 < nIter) {
            int kc2 = (i + 1) * 32;
            gload16(Ag0 + kc2, a_s[nxt] + aoff0);
            gload16(Ag1 + kc2, a_s[nxt] + aoff1);
            gload16(Bg0 + kc2, b_s[nxt] + boff0);
            if constexpr (NT == 4) gload16(Bg1 + kc2, b_s[nxt] + boff1);
        }
        short8 af[4], bf[NT];
        #pragma unroll
        for (int mt = 0; mt < 4; mt++)
            af[mt] = *(const short8*)(a_s[cur] + (wm * 64 + mt * 16 + r16) * 32 + (quad ^ sw) * 8);
        #pragma unroll
        for (int nt = 0; nt < NT; nt++)
            bf[nt] = *(const short8*)(b_s[cur] + (wn * (TN / 2) + nt * 16 + r16) * 32 + (quad ^ sw) * 8);
        #pragma unroll
        for (int mt = 0; mt < 4; mt++)
            #pragma unroll
            for (int nt = 0; nt < NT; nt++)
                acc[mt][nt] = __builtin_amdgcn_mfma_f32_16x16x32_bf16(af[mt], bf[nt], acc[mt][nt], 0, 0, 0);
    }

    #pragma unroll
    for (int mt = 0; mt < 4; mt++)
      #pragma unroll
      for (int nt = 0; nt < NT; nt++)
        #pragma unroll
        for (int r = 0; r < 4; r++) {
            int row = bm * 128 + wm * 64 + mt * 16 + quad * 4 + r;
            int col = bn * TN + wn * (TN / 2) + nt * 16 + r16;
            size_t oi = (size_t)row * N + col;
            if (OUT == 3) {
                ((u16*)C)[(size_t)kz * M * N + oi] = f2b(acc[mt][nt][r]);
            } else {
                float v = acc[mt][nt][r] + ldrawf(bias, col, isb);
                if (GELU) v = gelu_f(v);
                if (RES == 1) v += ldrawf(resid, (size_t)row * N + col, isb);
                if (OUT == 0) ((float*)C)[oi] = v;
                else          ((u16*)C)[oi] = f2b(v);
            }
        }
}

// ---------------- split-K reduce: out = x1 + b2 + sum_z part[z] ----------------
__global__ __launch_bounds__(256) void reduce_k(const u16* __restrict__ part,
                                                const float* __restrict__ x1,
                                                const void* __restrict__ b2,
                                                void* __restrict__ out,
                                                const int* flagp) {
    bool isb = (*flagp != 0);
    size_t i0 = ((size_t)blockIdx.x * 256 + threadIdx.x) * 4;
    float4 xv = *(const float4*)(x1 + i0);
    float r[4] = { xv.x, xv.y, xv.z, xv.w };
    #pragma unroll
    for (int j = 0; j < 4; j++) r[j] += ldrawf(b2, (i0 + j) & (D_ - 1), isb);
    #pragma unroll
    for (int z = 0; z < 4; z++) {
        ushort4 pv = *(const ushort4*)(part + (size_t)z * M_ * D_ + i0);
        r[0] += b2f(pv.x); r[1] += b2f(pv.y); r[2] += b2f(pv.z); r[3] += b2f(pv.w);
    }
    if (isb) {
        ushort4 ov = { f2b(r[0]), f2b(r[1]), f2b(r[2]), f2b(r[3]) };
        *(ushort4*)((u16*)out + i0) = ov;
    } else {
        float4 ov = { r[0], r[1], r[2], r[3] };
        *(float4*)((float*)out + i0) = ov;
    }
}

// ---------------- repack V only: qkv v-cols -> Vt [pid][64][l'] ----------------
__global__ __launch_bounds__(256) void repack_v_k(const u16* __restrict__ qkv,
                                                  u16* __restrict__ Vt) {
    int pid = blockIdx.x;            // 0..63
    int lt  = blockIdx.y;            // 0..15
    int b = pid >> 5, p = (pid >> 4) & 1, h = pid & 15;
    int t = threadIdx.x;
    int srow = t >> 2;
    int scol = (t & 3) * 16;

    int lp = lt * 64 + srow;
    int l  = 2 * lp + p;
    const u16* src = qkv + ((size_t)b * L_ + l) * (3 * D_) + 2 * D_ + h * HD_;

    __shared__ u16 vt[64][72];
    *(int4*)(&vt[srow][scol])     = *(const int4*)(src + scol);
    *(int4*)(&vt[srow][scol + 8]) = *(const int4*)(src + scol + 8);
    __syncthreads();
    union { u16 s[16]; int4 v[2]; } tmp;
    #pragma unroll
    for (int jj = 0; jj < 16; jj++) tmp.s[jj] = vt[scol + jj][srow];
    u16* vdst = Vt + ((size_t)pid * HD_ + srow) * LP_ + lt * 64 + scol;
    *(int4*)(vdst)     = tmp.v[0];
    *(int4*)(vdst + 8) = tmp.v[1];
}

// ---------------- flash attention (parity-compressed), reg-prefetch K/V ----------------
#define FS 72
__global__ __launch_bounds__(256) void fattn_k(const u16* __restrict__ qkv,
                                               const u16* __restrict__ Vt,
                                               u16* __restrict__ o) {
    __shared__ __align__(16) u16 Qs[64 * FS];
    __shared__ __align__(16) u16 Ks[64 * FS];
    __shared__ __align__(16) u16 Vs[64 * FS];
    __shared__ __align__(16) u16 Ps[4][16 * FS];

    const int pid = blockIdx.x, qt = blockIdx.y;
    const int b = pid >> 5, p = (pid >> 4) & 1, h = pid & 15;
    const int t = threadIdx.x, w = t >> 6, lane = t & 63;
    const int quad = lane >> 4, r16 = lane & 15;
    const int q0 = qt * 64;

    const int srow = t >> 2;
    const int scol = (t & 3) * 16;

    const u16* qsrc = qkv + ((size_t)b * L_ + 2 * (q0 + srow) + p) * (3 * D_) + h * HD_;
    *(int4*)(Qs + srow * FS + scol)     = *(const int4*)(qsrc + scol);
    *(int4*)(Qs + srow * FS + scol + 8) = *(const int4*)(qsrc + scol + 8);
    __syncthreads();

    const short8 qf0 = *(const short8*)(Qs + (w * 16 + r16) * FS + quad * 8);
    const short8 qf1 = *(const short8*)(Qs + (w * 16 + r16) * FS + quad * 8 + 32);

    floatx4 oacc[4] = {};
    float mrow[4] = {-INFINITY, -INFINITY, -INFINITY, -INFINITY};
    float lrow[4] = {};

    const int kt0 = (qt >= 4) ? qt - 4 : 0;
    const int qrow_base = q0 + w * 16 + quad * 4;

    auto kaddr = [&](int kt) {
        return qkv + ((size_t)b * L_ + 2 * (kt * 64 + srow) + p) * (3 * D_) + D_ + h * HD_;
    };
    auto vaddr = [&](int kt) {
        return Vt + ((size_t)pid * HD_ + srow) * LP_ + kt * 64;
    };
    int4 kr0 = *(const int4*)(kaddr(kt0) + scol);
    int4 kr1 = *(const int4*)(kaddr(kt0) + scol + 8);
    int4 vr0 = *(const int4*)(vaddr(kt0) + scol);
    int4 vr1 = *(const int4*)(vaddr(kt0) + scol + 8);

    for (int kt = kt0; kt <= qt; ++kt) {
        __syncthreads();
        *(int4*)(Ks + srow * FS + scol)     = kr0;
        *(int4*)(Ks + srow * FS + scol + 8) = kr1;
        *(int4*)(Vs + srow * FS + scol)     = vr0;
        *(int4*)(Vs + srow * FS + scol + 8) = vr1;
        __syncthreads();
        if (kt < qt) {
            kr0 = *(const int4*)(kaddr(kt + 1) + scol);
            kr1 = *(const int4*)(kaddr(kt + 1) + scol + 8);
            vr0 = *(const int4*)(vaddr(kt + 1) + scol);
            vr1 = *(const int4*)(vaddr(kt + 1) + scol + 8);
        }

        floatx4 s4[4];
        #pragma unroll
        for (int nt = 0; nt < 4; nt++) {
            short8 kf0 = *(const short8*)(Ks + (nt * 16 + r16) * FS + quad * 8);
            short8 kf1 = *(const short8*)(Ks + (nt * 16 + r16) * FS + quad * 8 + 32);
            floatx4 z = {};
            z = __builtin_amdgcn_mfma_f32_16x16x32_bf16(qf0, kf0, z, 0, 0, 0);
            z = __builtin_amdgcn_mfma_f32_16x16x32_bf16(qf1, kf1, z, 0, 0, 0);
            s4[nt] = z;
        }

        float sv[4][4];
        #pragma unroll
        for (int nt = 0; nt < 4; nt++) {
            int kcol = kt * 64 + nt * 16 + r16;
            #pragma unroll
            for (int r = 0; r < 4; r++) {
                int kq = kcol - (qrow_base + r);
                bool valid = (kq <= 0) && (kq >= -WP_);
                sv[nt][r] = valid ? s4[nt][r] * 0.125f : -1e30f;
            }
        }

        float mx[4];
        #pragma unroll
        for (int r = 0; r < 4; r++)
            mx[r] = fmaxf(fmaxf(sv[0][r], sv[1][r]), fmaxf(sv[2][r], sv[3][r]));
        #pragma unroll
        for (int off = 8; off >= 1; off >>= 1)
            #pragma unroll
            for (int r = 0; r < 4; r++) mx[r] = fmaxf(mx[r], __shfl_xor(mx[r], off));

        float al[4];
        #pragma unroll
        for (int r = 0; r < 4; r++) {
            float mnew = fmaxf(mrow[r], mx[r]);
            al[r] = __expf(mrow[r] - mnew);
            mrow[r] = mnew;
        }

        float ps[4][4], rs[4] = {};
        #pragma unroll
        for (int nt = 0; nt < 4; nt++)
            #pragma unroll
            for (int r = 0; r < 4; r++) {
                float pv = __expf(sv[nt][r] - mrow[r]);
                ps[nt][r] = pv; rs[r] += pv;
            }
        #pragma unroll
        for (int off = 8; off >= 1; off >>= 1)
            #pragma unroll
            for (int r = 0; r < 4; r++) rs[r] += __shfl_xor(rs[r], off);
        #pragma unroll
        for (int r = 0; r < 4; r++) lrow[r] = lrow[r] * al[r] + rs[r];
        #pragma unroll
        for (int nt = 0; nt < 4; nt++)
            #pragma unroll
            for (int r = 0; r < 4; r++) oacc[nt][r] *= al[r];

        #pragma unroll
        for (int nt = 0; nt < 4; nt++)
            #pragma unroll
            for (int r = 0; r < 4; r++)
                Ps[w][(quad * 4 + r) * FS + nt * 16 + r16] = f2b(ps[nt][r]);
        short8 pf0 = *(const short8*)(&Ps[w][r16 * FS + quad * 8]);
        short8 pf1 = *(const short8*)(&Ps[w][r16 * FS + quad * 8 + 32]);

        #pragma unroll
        for (int nt = 0; nt < 4; nt++) {
            short8 vf0 = *(const short8*)(Vs + (nt * 16 + r16) * FS + quad * 8);
            short8 vf1 = *(const short8*)(Vs + (nt * 16 + r16) * FS + quad * 8 + 32);
            oacc[nt] = __builtin_amdgcn_mfma_f32_16x16x32_bf16(pf0, vf0, oacc[nt], 0, 0, 0);
            oacc[nt] = __builtin_amdgcn_mfma_f32_16x16x32_bf16(pf1, vf1, oacc[nt], 0, 0, 0);
        }
    }

    float inv[4];
    #pragma unroll
    for (int r = 0; r < 4; r++) inv[r] = 1.0f / lrow[r];
    #pragma unroll
    for (int nt = 0; nt < 4; nt++)
        #pragma unroll
        for (int r = 0; r < 4; r++) {
            int qp = qrow_base + r;
            int l  = 2 * qp + p;
            int d  = nt * 16 + r16;
            o[((size_t)b * L_ + l) * D_ + h * HD_ + d] = f2b(oacc[nt][r] * inv[r]);
        }
}

// ---------------- orchestration ----------------
extern "C" void kernel_launch(void* const* d_in, const int* in_sizes, int n_in,
                              void* d_out, int out_size, void* d_ws, size_t ws_size,
                              hipStream_t stream) {
    (void)in_sizes; (void)n_in; (void)out_size; (void)ws_size;
    const void* x     = d_in[0];
    const void* ln1_g = d_in[1];
    const void* ln1_b = d_in[2];
    const void* Wqkv  = d_in[3];
    const void* bqkv  = d_in[4];
    const void* Wout  = d_in[5];
    const void* bout  = d_in[6];
    const void* ln2_g = d_in[7];
    const void* ln2_b = d_in[8];
    const void* W1    = d_in[9];
    const void* b1    = d_in[10];
    const void* W2    = d_in[11];
    const void* b2    = d_in[12];

    char* ws = (char*)d_ws;
    const size_t MB = 1024 * 1024;
    u16*   wqkvT = (u16*)ws;                      // 6MB   [3D, D]
    u16*   qkv   = (u16*)(ws + 6  * MB);          // 24MB  [M, 3D]
    u16*   woutT = (u16*)(ws + 30 * MB);          // 2MB   [D, D]
    u16*   fbuf  = (u16*)ws;                      // 32MB  [M,4D] overlay (GEMM3+)
    u16*   w1T   = (u16*)(ws + 32 * MB);          // 8MB   [4D, D]
    u16*   w2T   = (u16*)(ws + 40 * MB);          // 8MB   [D, 4D]
    u16*   bufA  = (u16*)(ws + 48 * MB);          // 8MB   [M, D]
    float* x1    = (float*)(ws + 56 * MB);        // 16MB  [M, D] f32
    u16*   Vt    = (u16*)(ws + 72 * MB);          // 8MB   [64][64][1024]
    u16*   part  = (u16*)(ws + 80 * MB);          // 32MB  4 x [M, D] bf16 split-K partials
    int*   flag  = (int*)(ws + 112 * MB);

    dim3 tb(256);
    probe_k<<<1, 64, 0, stream>>>((const u16*)x, flag);

    transpose_all_k<<<12288, tb, 0, stream>>>(Wqkv, Wout, W1, W2, wqkvT, woutT, w1T, w2T, flag);

    ln_k<0><<<M_, tb, 0, stream>>>(x, ln1_g, ln1_b, bufA, flag);

    // GEMM1: qkv = h @ Wqkv + bqkv    [4096 x 3072 x 1024], 4-wave 128x128
    gemm128_k<4, 1, 0, 0, 1><<<dim3(3 * D_ / 128, M_ / 128), tb, 0, stream>>>(bufA, wqkvT, bqkv, nullptr, qkv, M_, 3 * D_, D_, flag);

    repack_v_k<<<dim3(64, 16), tb, 0, stream>>>(qkv, Vt);
    fattn_k<<<dim3(64, 16), tb, 0, stream>>>(qkv, Vt, bufA);

    // GEMM2: x1 = o @ Wout + bout + x  [4096 x 1024 x 1024], 4-wave 128x64
    gemm128_k<2, 0, 1, 0, 1><<<dim3(D_ / 64, M_ / 128), tb, 0, stream>>>(bufA, woutT, bout, x, x1, M_, D_, D_, flag);

    ln_k<1><<<M_, tb, 0, stream>>>(x1, ln2_g, ln2_b, bufA, flag);

    // GEMM3: f = gelu(h2 @ W1 + b1)   [4096 x 4096 x 1024], 4-wave 128x128
    gemm128_k<4, 1, 0, 1, 1><<<dim3(4 * D_ / 128, M_ / 128), tb, 0, stream>>>(bufA, w1T, b1, nullptr, fbuf, M_, 4 * D_, D_, flag);

    // GEMM4 split-K=4: part[z] = f @ W2 (K-chunk z)  [4096 x 1024 x 4096]
    gemm128_k<2, 3, 0, 0, 4><<<dim3(D_ / 64, M_ / 128, 4), tb, 0, stream>>>(fbuf, w2T, nullptr, nullptr, part, M_, D_, 4 * D_, flag);
    reduce_k<<<(M_ * D_) / 1024, tb, 0, stream>>>(part, x1, b2, d_out, flag);
}

// Round 10
// 368.727 us; speedup vs baseline: 1.2650x; 1.0604x over previous
//
#include <hip/hip_runtime.h>

typedef unsigned short u16;
typedef short short8 __attribute__((ext_vector_type(8)));
typedef float floatx4 __attribute__((ext_vector_type(4)));

#define B_  2
#define L_  2048
#define D_  1024
#define H_  16
#define HD_ 64
#define M_  (B_*L_)      // 4096 rows
#define LP_ 1024         // compressed (per-parity) seq len
#define WP_ 256          // compressed window

__device__ __forceinline__ float b2f(u16 u) {
    union { unsigned int i; float f; } c; c.i = ((unsigned int)u) << 16; return c.f;
}
__device__ __forceinline__ u16 f2b(float f) {
    union { float f; unsigned int i; } c; c.f = f;
    unsigned int u = c.i;
    u = u + 0x7FFFu + ((u >> 16) & 1u);   // RNE
    return (u16)(u >> 16);
}
__device__ __forceinline__ float ldrawf(const void* p, size_t i, bool isbf16) {
    return isbf16 ? b2f(((const u16*)p)[i]) : ((const float*)p)[i];
}
__device__ __forceinline__ u16 ldraw16(const void* p, size_t i, bool isbf16) {
    return isbf16 ? ((const u16*)p)[i] : f2b(((const float*)p)[i]);
}
// inline dtype probe: per-wave ballot over even u16s of x (2 cachelines, L2-hot).
// bf16 data -> bf16 exponents in [100,140] for ~all lanes; fp32 mantissa halves -> ~16%.
__device__ __forceinline__ bool is_bf16_in(const u16* xp) {
    int lane = threadIdx.x & 63;
    unsigned int u = xp[2 * lane];
    unsigned int e = (u >> 7) & 0xFF;
    unsigned long long m = __ballot(e >= 100 && e <= 140);
    return __popcll(m) >= 32;
}
// cheap GELU (tanh form), max dev from erf form ~1e-3
__device__ __forceinline__ float gelu_f(float x) {
    float x3 = x * x * x;
    float y2 = 1.5957691216057308f * (x + 0.044715f * x3);
    float e  = __expf(y2);
    float th = 1.0f - 2.0f / (e + 1.0f);
    return 0.5f * x * (1.0f + th);
}
// async global->LDS, 16B per lane (LDS dst must be wave-base + lane*16)
__device__ __forceinline__ void gload16(const u16* g, u16* l) {
    __builtin_amdgcn_global_load_lds(
        (__attribute__((address_space(1))) void*)(g),
        (__attribute__((address_space(3))) void*)(l), 16, 0, 0);
}

// ---------------- fused prep: 4 weight transposes + LN1, one launch ----------------
__device__ __forceinline__ void tr_body(const void* in, u16* out, int K, int N,
                                        int bx, int by, bool isb) {
    __shared__ u16 tile[32][33];
    int tx = threadIdx.x & 31;
    int ty = threadIdx.x >> 5;
    int nb = bx * 32, kb = by * 32;
    #pragma unroll
    for (int j = 0; j < 32; j += 8)
        tile[ty + j][tx] = ldraw16(in, (size_t)(kb + ty + j) * N + nb + tx, isb);
    __syncthreads();
    #pragma unroll
    for (int j = 0; j < 32; j += 8)
        out[(size_t)(nb + ty + j) * K + kb + tx] = tile[tx][ty + j];
}
// SRC 0: raw (flag), 1: fp32 ws, 2: bf16 ws
template<int SRC>
__device__ __forceinline__ void ln_body(const void* x, const void* g, const void* bb,
                                        u16* out, int row, bool isb) {
    int t = threadIdx.x;
    float v[4]; float s = 0.f, s2 = 0.f;
    #pragma unroll
    for (int i = 0; i < 4; i++) {
        size_t idx = (size_t)row * D_ + t + 256 * i;
        float f = (SRC == 1) ? ((const float*)x)[idx]
                : (SRC == 2) ? b2f(((const u16*)x)[idx])
                             : ldrawf(x, idx, isb);
        v[i] = f; s += f; s2 += f * f;
    }
    #pragma unroll
    for (int off = 32; off >= 1; off >>= 1) { s += __shfl_xor(s, off); s2 += __shfl_xor(s2, off); }
    __shared__ float red[8];
    int wave = t >> 6;
    if ((t & 63) == 0) { red[wave] = s; red[4 + wave] = s2; }
    __syncthreads();
    s  = red[0] + red[1] + red[2] + red[3];
    s2 = red[4] + red[5] + red[6] + red[7];
    float mu  = s * (1.0f / 1024.0f);
    float var = s2 * (1.0f / 1024.0f) - mu * mu;
    float rs  = rsqrtf(var + 1e-5f);
    #pragma unroll
    for (int i = 0; i < 4; i++) {
        int c = t + 256 * i;
        out[(size_t)row * D_ + c] = f2b((v[i] - mu) * rs * ldrawf(g, c, isb) + ldrawf(bb, c, isb));
    }
}
__global__ __launch_bounds__(256) void prep_k(
        const void* w0, const void* w1, const void* w2, const void* w3,
        u16* o0, u16* o1, u16* o2, u16* o3,
        const void* x, const void* ln1_g, const void* ln1_b, u16* h_out) {
    bool isb = is_bf16_in((const u16*)x);
    int id = blockIdx.x;
    if (id < 3072)            { int l = id;         tr_body(w0, o0, 1024, 3072, l % 96,  l / 96,  isb); }
    else if (id < 4096)       { int l = id - 3072;  tr_body(w1, o1, 1024, 1024, l % 32,  l / 32,  isb); }
    else if (id < 8192)       { int l = id - 4096;  tr_body(w2, o2, 1024, 4096, l % 128, l / 128, isb); }
    else if (id < 12288)      { int l = id - 8192;  tr_body(w3, o3, 4096, 1024, l % 32,  l / 32,  isb); }
    else                      { ln_body<0>(x, ln1_g, ln1_b, h_out, id - 12288, isb); }
}

// ---------------- standalone LayerNorm (LN2, bf16 ws input) ----------------
__global__ __launch_bounds__(256) void ln2_k(const u16* __restrict__ x1b, const void* __restrict__ g,
                                             const void* __restrict__ bb, u16* __restrict__ out,
                                             const void* xprobe) {
    bool isb = is_bf16_in((const u16*)xprobe);
    ln_body<2>(x1b, g, bb, out, blockIdx.x, isb);
}

// ---------------- 4-wave dbuf MFMA GEMM: C[M,N] = A[M,K] @ BT[N,K]^T ----------------
// 128x(NT*32) tile, BK=32, 4 waves 2x2, wave = 4xNT accs of 16x16x32.
// Single-barrier dbuf K-loop; gload16 staging; XOR k-chunk swizzle (0 conflicts, r5).
// OUT: 1 bf16 ws, 3 bf16 split-K partial. RES: 0 none, 1 raw input.
template<int NT, int OUT, int RES, int GELU, int SPLITK>
__global__ __launch_bounds__(256, 3) void gemm128_k(const u16* __restrict__ A,
                                                    const u16* __restrict__ BT,
                                                    const void* __restrict__ bias,
                                                    const void* __restrict__ resid,
                                                    void* __restrict__ C,
                                                    int M, int N, int K,
                                                    const void* xprobe) {
    constexpr int TN = NT * 32;
    __shared__ __align__(16) u16 a_s[2][128 * 32];
    __shared__ __align__(16) u16 b_s[2][TN * 32];
    bool isb = is_bf16_in((const u16*)xprobe);

    const int bm = blockIdx.y, bn = blockIdx.x;
    const int kz = (SPLITK > 1) ? blockIdx.z : 0;
    const int Kc = K / SPLITK;
    const int k_beg = kz * Kc;
    const int nIter = Kc / 32;

    const int t = threadIdx.x, w = t >> 6, lane = t & 63;
    const int wm = w >> 1, wn = w & 1;
    const int quad = lane >> 4, r16 = lane & 15;

    const int lr  = lane >> 2;
    const int lcg = (((lane & 3) ^ ((lr >> 1) & 3))) * 8;
    const u16* Ag0 = A  + (size_t)(bm * 128 + w * 32 + lr) * K + lcg + k_beg;
    const u16* Ag1 = Ag0 + (size_t)16 * K;
    const u16* Bg0 = BT + (size_t)(bn * TN + w * (TN / 4) + lr) * K + lcg + k_beg;
    const u16* Bg1 = Bg0 + (size_t)16 * K;
    const int aoff0 = (w * 32 + lr) * 32 + (lane & 3) * 8;
    const int aoff1 = aoff0 + 16 * 32;
    const int boff0 = (w * (TN / 4) + lr) * 32 + (lane & 3) * 8;
    const int boff1 = boff0 + 16 * 32;

    const int sw = ((r16 >> 1) & 3);
    floatx4 acc[4][NT] = {};

    gload16(Ag0, a_s[0] + aoff0);
    gload16(Ag1, a_s[0] + aoff1);
    gload16(Bg0, b_s[0] + boff0);
    if constexpr (NT == 4) gload16(Bg1, b_s[0] + boff1);

    for (int i = 0; i < nIter; i++) {
        const int cur = i & 1, nxt = cur ^ 1;
        __syncthreads();   // drains cur-tile loads (issued one compute phase ago)
        if (i + 1 < nIter) {
            int kc2 = (i + 1) * 32;
            gload16(Ag0 + kc2, a_s[nxt] + aoff0);
            gload16(Ag1 + kc2, a_s[nxt] + aoff1);
            gload16(Bg0 + kc2, b_s[nxt] + boff0);
            if constexpr (NT == 4) gload16(Bg1 + kc2, b_s[nxt] + boff1);
        }
        short8 af[4], bf[NT];
        #pragma unroll
        for (int mt = 0; mt < 4; mt++)
            af[mt] = *(const short8*)(a_s[cur] + (wm * 64 + mt * 16 + r16) * 32 + (quad ^ sw) * 8);
        #pragma unroll
        for (int nt = 0; nt < NT; nt++)
            bf[nt] = *(const short8*)(b_s[cur] + (wn * (TN / 2) + nt * 16 + r16) * 32 + (quad ^ sw) * 8);
        #pragma unroll
        for (int mt = 0; mt < 4; mt++)
            #pragma unroll
            for (int nt = 0; nt < NT; nt++)
                acc[mt][nt] = __builtin_amdgcn_mfma_f32_16x16x32_bf16(af[mt], bf[nt], acc[mt][nt], 0, 0, 0);
    }

    #pragma unroll
    for (int mt = 0; mt < 4; mt++)
      #pragma unroll
      for (int nt = 0; nt < NT; nt++)
        #pragma unroll
        for (int r = 0; r < 4; r++) {
            int row = bm * 128 + wm * 64 + mt * 16 + quad * 4 + r;
            int col = bn * TN + wn * (TN / 2) + nt * 16 + r16;
            size_t oi = (size_t)row * N + col;
            if (OUT == 3) {
                ((u16*)C)[(size_t)kz * M * N + oi] = f2b(acc[mt][nt][r]);
            } else {
                float v = acc[mt][nt][r] + ldrawf(bias, col, isb);
                if (GELU) v = gelu_f(v);
                if (RES == 1) v += ldrawf(resid, (size_t)row * N + col, isb);
                ((u16*)C)[oi] = f2b(v);
            }
        }
}

// ---------------- split-K reduce: out = x1b + b2 + sum_z part[z] ----------------
__global__ __launch_bounds__(256) void reduce_k(const u16* __restrict__ part,
                                                const u16* __restrict__ x1b,
                                                const void* __restrict__ b2,
                                                void* __restrict__ out,
                                                const void* xprobe) {
    bool isb = is_bf16_in((const u16*)xprobe);
    size_t i0 = ((size_t)blockIdx.x * 256 + threadIdx.x) * 4;
    ushort4 xv = *(const ushort4*)(x1b + i0);
    float r[4] = { b2f(xv.x), b2f(xv.y), b2f(xv.z), b2f(xv.w) };
    #pragma unroll
    for (int j = 0; j < 4; j++) r[j] += ldrawf(b2, (i0 + j) & (D_ - 1), isb);
    #pragma unroll
    for (int z = 0; z < 4; z++) {
        ushort4 pv = *(const ushort4*)(part + (size_t)z * M_ * D_ + i0);
        r[0] += b2f(pv.x); r[1] += b2f(pv.y); r[2] += b2f(pv.z); r[3] += b2f(pv.w);
    }
    if (isb) {
        ushort4 ov = { f2b(r[0]), f2b(r[1]), f2b(r[2]), f2b(r[3]) };
        *(ushort4*)((u16*)out + i0) = ov;
    } else {
        float4 ov = { r[0], r[1], r[2], r[3] };
        *(float4*)((float*)out + i0) = ov;
    }
}

// ---------------- repack V only: qkv v-cols -> Vt [pid][64][l'] ----------------
__global__ __launch_bounds__(256) void repack_v_k(const u16* __restrict__ qkv,
                                                  u16* __restrict__ Vt) {
    int pid = blockIdx.x;            // 0..63
    int lt  = blockIdx.y;            // 0..15
    int b = pid >> 5, p = (pid >> 4) & 1, h = pid & 15;
    int t = threadIdx.x;
    int srow = t >> 2;
    int scol = (t & 3) * 16;

    int lp = lt * 64 + srow;
    int l  = 2 * lp + p;
    const u16* src = qkv + ((size_t)b * L_ + l) * (3 * D_) + 2 * D_ + h * HD_;

    __shared__ u16 vt[64][72];
    *(int4*)(&vt[srow][scol])     = *(const int4*)(src + scol);
    *(int4*)(&vt[srow][scol + 8]) = *(const int4*)(src + scol + 8);
    __syncthreads();
    union { u16 s[16]; int4 v[2]; } tmp;
    #pragma unroll
    for (int jj = 0; jj < 16; jj++) tmp.s[jj] = vt[scol + jj][srow];
    u16* vdst = Vt + ((size_t)pid * HD_ + srow) * LP_ + lt * 64 + scol;
    *(int4*)(vdst)     = tmp.v[0];
    *(int4*)(vdst + 8) = tmp.v[1];
}

// ---------------- flash attention (parity-compressed), reg-prefetch K/V ----------------
#define FS 72
__global__ __launch_bounds__(256) void fattn_k(const u16* __restrict__ qkv,
                                               const u16* __restrict__ Vt,
                                               u16* __restrict__ o) {
    __shared__ __align__(16) u16 Qs[64 * FS];
    __shared__ __align__(16) u16 Ks[64 * FS];
    __shared__ __align__(16) u16 Vs[64 * FS];
    __shared__ __align__(16) u16 Ps[4][16 * FS];

    const int pid = blockIdx.x, qt = blockIdx.y;
    const int b = pid >> 5, p = (pid >> 4) & 1, h = pid & 15;
    const int t = threadIdx.x, w = t >> 6, lane = t & 63;
    const int quad = lane >> 4, r16 = lane & 15;
    const int q0 = qt * 64;

    const int srow = t >> 2;
    const int scol = (t & 3) * 16;

    const u16* qsrc = qkv + ((size_t)b * L_ + 2 * (q0 + srow) + p) * (3 * D_) + h * HD_;
    *(int4*)(Qs + srow * FS + scol)     = *(const int4*)(qsrc + scol);
    *(int4*)(Qs + srow * FS + scol + 8) = *(const int4*)(qsrc + scol + 8);
    __syncthreads();

    const short8 qf0 = *(const short8*)(Qs + (w * 16 + r16) * FS + quad * 8);
    const short8 qf1 = *(const short8*)(Qs + (w * 16 + r16) * FS + quad * 8 + 32);

    floatx4 oacc[4] = {};
    float mrow[4] = {-INFINITY, -INFINITY, -INFINITY, -INFINITY};
    float lrow[4] = {};

    const int kt0 = (qt >= 4) ? qt - 4 : 0;
    const int qrow_base = q0 + w * 16 + quad * 4;

    auto kaddr = [&](int kt) {
        return qkv + ((size_t)b * L_ + 2 * (kt * 64 + srow) + p) * (3 * D_) + D_ + h * HD_;
    };
    auto vaddr = [&](int kt) {
        return Vt + ((size_t)pid * HD_ + srow) * LP_ + kt * 64;
    };
    int4 kr0 = *(const int4*)(kaddr(kt0) + scol);
    int4 kr1 = *(const int4*)(kaddr(kt0) + scol + 8);
    int4 vr0 = *(const int4*)(vaddr(kt0) + scol);
    int4 vr1 = *(const int4*)(vaddr(kt0) + scol + 8);

    for (int kt = kt0; kt <= qt; ++kt) {
        __syncthreads();
        *(int4*)(Ks + srow * FS + scol)     = kr0;
        *(int4*)(Ks + srow * FS + scol + 8) = kr1;
        *(int4*)(Vs + srow * FS + scol)     = vr0;
        *(int4*)(Vs + srow * FS + scol + 8) = vr1;
        __syncthreads();
        if (kt < qt) {
            kr0 = *(const int4*)(kaddr(kt + 1) + scol);
            kr1 = *(const int4*)(kaddr(kt + 1) + scol + 8);
            vr0 = *(const int4*)(vaddr(kt + 1) + scol);
            vr1 = *(const int4*)(vaddr(kt + 1) + scol + 8);
        }

        floatx4 s4[4];
        #pragma unroll
        for (int nt = 0; nt < 4; nt++) {
            short8 kf0 = *(const short8*)(Ks + (nt * 16 + r16) * FS + quad * 8);
            short8 kf1 = *(const short8*)(Ks + (nt * 16 + r16) * FS + quad * 8 + 32);
            floatx4 z = {};
            z = __builtin_amdgcn_mfma_f32_16x16x32_bf16(qf0, kf0, z, 0, 0, 0);
            z = __builtin_amdgcn_mfma_f32_16x16x32_bf16(qf1, kf1, z, 0, 0, 0);
            s4[nt] = z;
        }

        float sv[4][4];
        #pragma unroll
        for (int nt = 0; nt < 4; nt++) {
            int kcol = kt * 64 + nt * 16 + r16;
            #pragma unroll
            for (int r = 0; r < 4; r++) {
                int kq = kcol - (qrow_base + r);
                bool valid = (kq <= 0) && (kq >= -WP_);
                sv[nt][r] = valid ? s4[nt][r] * 0.125f : -1e30f;
            }
        }

        float mx[4];
        #pragma unroll
        for (int r = 0; r < 4; r++)
            mx[r] = fmaxf(fmaxf(sv[0][r], sv[1][r]), fmaxf(sv[2][r], sv[3][r]));
        #pragma unroll
        for (int off = 8; off >= 1; off >>= 1)
            #pragma unroll
            for (int r = 0; r < 4; r++) mx[r] = fmaxf(mx[r], __shfl_xor(mx[r], off));

        float al[4];
        #pragma unroll
        for (int r = 0; r < 4; r++) {
            float mnew = fmaxf(mrow[r], mx[r]);
            al[r] = __expf(mrow[r] - mnew);
            mrow[r] = mnew;
        }

        float ps[4][4], rs[4] = {};
        #pragma unroll
        for (int nt = 0; nt < 4; nt++)
            #pragma unroll
            for (int r = 0; r < 4; r++) {
                float pv = __expf(sv[nt][r] - mrow[r]);
                ps[nt][r] = pv; rs[r] += pv;
            }
        #pragma unroll
        for (int off = 8; off >= 1; off >>= 1)
            #pragma unroll
            for (int r = 0; r < 4; r++) rs[r] += __shfl_xor(rs[r], off);
        #pragma unroll
        for (int r = 0; r < 4; r++) lrow[r] = lrow[r] * al[r] + rs[r];
        #pragma unroll
        for (int nt = 0; nt < 4; nt++)
            #pragma unroll
            for (int r = 0; r < 4; r++) oacc[nt][r] *= al[r];

        #pragma unroll
        for (int nt = 0; nt < 4; nt++)
            #pragma unroll
            for (int r = 0; r < 4; r++)
                Ps[w][(quad * 4 + r) * FS + nt * 16 + r16] = f2b(ps[nt][r]);
        short8 pf0 = *(const short8*)(&Ps[w][r16 * FS + quad * 8]);
        short8 pf1 = *(const short8*)(&Ps[w][r16 * FS + quad * 8 + 32]);

        #pragma unroll
        for (int nt = 0; nt < 4; nt++) {
            short8 vf0 = *(const short8*)(Vs + (nt * 16 + r16) * FS + quad * 8);
            short8 vf1 = *(const short8*)(Vs + (nt * 16 + r16) * FS + quad * 8 + 32);
            oacc[nt] = __builtin_amdgcn_mfma_f32_16x16x32_bf16(pf0, vf0, oacc[nt], 0, 0, 0);
            oacc[nt] = __builtin_amdgcn_mfma_f32_16x16x32_bf16(pf1, vf1, oacc[nt], 0, 0, 0);
        }
    }

    float inv[4];
    #pragma unroll
    for (int r = 0; r < 4; r++) inv[r] = 1.0f / lrow[r];
    #pragma unroll
    for (int nt = 0; nt < 4; nt++)
        #pragma unroll
        for (int r = 0; r < 4; r++) {
            int qp = qrow_base + r;
            int l  = 2 * qp + p;
            int d  = nt * 16 + r16;
            o[((size_t)b * L_ + l) * D_ + h * HD_ + d] = f2b(oacc[nt][r] * inv[r]);
        }
}

// ---------------- orchestration ----------------
extern "C" void kernel_launch(void* const* d_in, const int* in_sizes, int n_in,
                              void* d_out, int out_size, void* d_ws, size_t ws_size,
                              hipStream_t stream) {
    (void)in_sizes; (void)n_in; (void)out_size; (void)ws_size;
    const void* x     = d_in[0];
    const void* ln1_g = d_in[1];
    const void* ln1_b = d_in[2];
    const void* Wqkv  = d_in[3];
    const void* bqkv  = d_in[4];
    const void* Wout  = d_in[5];
    const void* bout  = d_in[6];
    const void* ln2_g = d_in[7];
    const void* ln2_b = d_in[8];
    const void* W1    = d_in[9];
    const void* b1    = d_in[10];
    const void* W2    = d_in[11];
    const void* b2    = d_in[12];

    char* ws = (char*)d_ws;
    const size_t MB = 1024 * 1024;
    u16*   wqkvT = (u16*)ws;                      // 6MB   [3D, D]
    u16*   qkv   = (u16*)(ws + 6  * MB);          // 24MB  [M, 3D]
    u16*   woutT = (u16*)(ws + 30 * MB);          // 2MB   [D, D]
    u16*   fbuf  = (u16*)ws;                      // 32MB  [M,4D] overlay (GEMM3+)
    u16*   w1T   = (u16*)(ws + 32 * MB);          // 8MB   [4D, D]
    u16*   w2T   = (u16*)(ws + 40 * MB);          // 8MB   [D, 4D]
    u16*   bufA  = (u16*)(ws + 48 * MB);          // 8MB   [M, D]
    u16*   x1b   = (u16*)(ws + 56 * MB);          // 8MB   [M, D] bf16 residual trunk
    u16*   Vt    = (u16*)(ws + 72 * MB);          // 8MB   [64][64][1024]
    u16*   part  = (u16*)(ws + 80 * MB);          // 32MB  4 x [M, D] bf16 split-K partials

    dim3 tb(256);

    // prep: 4 transposes (12288 blocks) + LN1 (4096 blocks), one launch
    prep_k<<<16384, tb, 0, stream>>>(Wqkv, Wout, W1, W2, wqkvT, woutT, w1T, w2T,
                                     x, ln1_g, ln1_b, bufA);

    // GEMM1: qkv = h @ Wqkv + bqkv    [4096 x 3072 x 1024]
    gemm128_k<4, 1, 0, 0, 1><<<dim3(3 * D_ / 128, M_ / 128), tb, 0, stream>>>(bufA, wqkvT, bqkv, nullptr, qkv, M_, 3 * D_, D_, x);

    repack_v_k<<<dim3(64, 16), tb, 0, stream>>>(qkv, Vt);
    fattn_k<<<dim3(64, 16), tb, 0, stream>>>(qkv, Vt, bufA);

    // GEMM2: x1b = o @ Wout + bout + x  [4096 x 1024 x 1024], bf16 trunk
    gemm128_k<2, 1, 1, 0, 1><<<dim3(D_ / 64, M_ / 128), tb, 0, stream>>>(bufA, woutT, bout, x, x1b, M_, D_, D_, x);

    // LN2: x1b -> h2 (bufA)
    ln2_k<<<M_, tb, 0, stream>>>(x1b, ln2_g, ln2_b, bufA, x);

    // GEMM3: f = gelu(h2 @ W1 + b1)   [4096 x 4096 x 1024]
    gemm128_k<4, 1, 0, 1, 1><<<dim3(4 * D_ / 128, M_ / 128), tb, 0, stream>>>(bufA, w1T, b1, nullptr, fbuf, M_, 4 * D_, D_, x);

    // GEMM4 split-K=4: part[z] = f @ W2 (K-chunk z)  [4096 x 1024 x 4096]
    gemm128_k<2, 3, 0, 0, 4><<<dim3(D_ / 64, M_ / 128, 4), tb, 0, stream>>>(fbuf, w2T, nullptr, nullptr, part, M_, D_, 4 * D_, x);
    // reduce: out = x1b + b2 + sum(part)
    reduce_k<<<(M_ * D_) / 1024, tb, 0, stream>>>(part, x1b, b2, d_out, x);
}

// Round 11
// 354.826 us; speedup vs baseline: 1.3146x; 1.0392x over previous
//
#include <hip/hip_runtime.h>

typedef unsigned short u16;
typedef short short8 __attribute__((ext_vector_type(8)));
typedef float floatx4 __attribute__((ext_vector_type(4)));

#define B_  2
#define L_  2048
#define D_  1024
#define H_  16
#define HD_ 64
#define M_  (B_*L_)      // 4096 rows
#define LP_ 1024         // compressed (per-parity) seq len
#define WP_ 256          // compressed window

__device__ __forceinline__ float b2f(u16 u) {
    union { unsigned int i; float f; } c; c.i = ((unsigned int)u) << 16; return c.f;
}
__device__ __forceinline__ u16 f2b(float f) {
    union { float f; unsigned int i; } c; c.f = f;
    unsigned int u = c.i;
    u = u + 0x7FFFu + ((u >> 16) & 1u);   // RNE
    return (u16)(u >> 16);
}
__device__ __forceinline__ float ldrawf(const void* p, size_t i, bool isbf16) {
    return isbf16 ? b2f(((const u16*)p)[i]) : ((const float*)p)[i];
}
__device__ __forceinline__ u16 ldraw16(const void* p, size_t i, bool isbf16) {
    return isbf16 ? ((const u16*)p)[i] : f2b(((const float*)p)[i]);
}
// inline dtype probe: per-wave ballot over even u16s of x (2 cachelines, L2-hot).
__device__ __forceinline__ bool is_bf16_in(const u16* xp) {
    int lane = threadIdx.x & 63;
    unsigned int u = xp[2 * lane];
    unsigned int e = (u >> 7) & 0xFF;
    unsigned long long m = __ballot(e >= 100 && e <= 140);
    return __popcll(m) >= 32;
}
// cheap GELU (tanh form), max dev from erf form ~1e-3
__device__ __forceinline__ float gelu_f(float x) {
    float x3 = x * x * x;
    float y2 = 1.5957691216057308f * (x + 0.044715f * x3);
    float e  = __expf(y2);
    float th = 1.0f - 2.0f / (e + 1.0f);
    return 0.5f * x * (1.0f + th);
}
// async global->LDS, 16B per lane (LDS dst must be wave-base + lane*16)
__device__ __forceinline__ void gload16(const u16* g, u16* l) {
    __builtin_amdgcn_global_load_lds(
        (__attribute__((address_space(1))) void*)(g),
        (__attribute__((address_space(3))) void*)(l), 16, 0, 0);
}

// ---------------- fused prep: 4 weight transposes + LN1, one launch ----------------
__device__ __forceinline__ void tr_body(const void* in, u16* out, int K, int N,
                                        int bx, int by, bool isb) {
    __shared__ u16 tile[32][33];
    int tx = threadIdx.x & 31;
    int ty = threadIdx.x >> 5;
    int nb = bx * 32, kb = by * 32;
    #pragma unroll
    for (int j = 0; j < 32; j += 8)
        tile[ty + j][tx] = ldraw16(in, (size_t)(kb + ty + j) * N + nb + tx, isb);
    __syncthreads();
    #pragma unroll
    for (int j = 0; j < 32; j += 8)
        out[(size_t)(nb + ty + j) * K + kb + tx] = tile[tx][ty + j];
}
// SRC 0: raw (flag), 2: bf16 ws
template<int SRC>
__device__ __forceinline__ void ln_body(const void* x, const void* g, const void* bb,
                                        u16* out, int row, bool isb) {
    int t = threadIdx.x;
    float v[4]; float s = 0.f, s2 = 0.f;
    #pragma unroll
    for (int i = 0; i < 4; i++) {
        size_t idx = (size_t)row * D_ + t + 256 * i;
        float f = (SRC == 2) ? b2f(((const u16*)x)[idx]) : ldrawf(x, idx, isb);
        v[i] = f; s += f; s2 += f * f;
    }
    #pragma unroll
    for (int off = 32; off >= 1; off >>= 1) { s += __shfl_xor(s, off); s2 += __shfl_xor(s2, off); }
    __shared__ float red[8];
    int wave = t >> 6;
    if ((t & 63) == 0) { red[wave] = s; red[4 + wave] = s2; }
    __syncthreads();
    s  = red[0] + red[1] + red[2] + red[3];
    s2 = red[4] + red[5] + red[6] + red[7];
    float mu  = s * (1.0f / 1024.0f);
    float var = s2 * (1.0f / 1024.0f) - mu * mu;
    float rs  = rsqrtf(var + 1e-5f);
    #pragma unroll
    for (int i = 0; i < 4; i++) {
        int c = t + 256 * i;
        out[(size_t)row * D_ + c] = f2b((v[i] - mu) * rs * ldrawf(g, c, isb) + ldrawf(bb, c, isb));
    }
}
__global__ __launch_bounds__(256) void prep_k(
        const void* w0, const void* w1, const void* w2, const void* w3,
        u16* o0, u16* o1, u16* o2, u16* o3,
        const void* x, const void* ln1_g, const void* ln1_b, u16* h_out) {
    bool isb = is_bf16_in((const u16*)x);
    int id = blockIdx.x;
    if (id < 3072)            { int l = id;         tr_body(w0, o0, 1024, 3072, l % 96,  l / 96,  isb); }
    else if (id < 4096)       { int l = id - 3072;  tr_body(w1, o1, 1024, 1024, l % 32,  l / 32,  isb); }
    else if (id < 8192)       { int l = id - 4096;  tr_body(w2, o2, 1024, 4096, l % 128, l / 128, isb); }
    else if (id < 12288)      { int l = id - 8192;  tr_body(w3, o3, 4096, 1024, l % 32,  l / 32,  isb); }
    else                      { ln_body<0>(x, ln1_g, ln1_b, h_out, id - 12288, isb); }
}

// ---------------- standalone LayerNorm (LN2, bf16 ws input) ----------------
__global__ __launch_bounds__(256) void ln2_k(const u16* __restrict__ x1b, const void* __restrict__ g,
                                             const void* __restrict__ bb, u16* __restrict__ out,
                                             const void* xprobe) {
    bool isb = is_bf16_in((const u16*)xprobe);
    ln_body<2>(x1b, g, bb, out, blockIdx.x, isb);
}

// ---------------- 4-wave dbuf MFMA GEMM: C[M,N] = A[M,K] @ BT[N,K]^T ----------------
// 128x(NT*32) tile, BK=32, 4 waves 2x2, wave = 4xNT accs of 16x16x32.
// Single-barrier dbuf K-loop; gload16 staging; XOR k-chunk swizzle (0 conflicts, r5).
// OUT: 1 bf16 ws, 3 bf16 split-K partial. RES: 0 none, 1 raw input.
// SPLITK==4: launched 1D (2048); XCD-aware decode puts one kz-slice + 16 bm-chunks
// per XCD (flat%8 -> XCD round-robin), cutting A replication across per-XCD L2s.
template<int NT, int OUT, int RES, int GELU, int SPLITK>
__global__ __launch_bounds__(256, 3) void gemm128_k(const u16* __restrict__ A,
                                                    const u16* __restrict__ BT,
                                                    const void* __restrict__ bias,
                                                    const void* __restrict__ resid,
                                                    void* __restrict__ C,
                                                    int M, int N, int K,
                                                    const void* xprobe) {
    constexpr int TN = NT * 32;
    __shared__ __align__(16) u16 a_s[2][128 * 32];
    __shared__ __align__(16) u16 b_s[2][TN * 32];
    bool isb = is_bf16_in((const u16*)xprobe);

    int bm, bn, kz;
    if (SPLITK == 4) {
        int f = blockIdx.x;                       // 0..2047
        int g = ((f >> 7) << 3) | (f & 7);        // (bm,kz) group, 0..127
        bn = (f >> 3) & 15;
        bm = g >> 2;
        kz = g & 3;                               // per-XCD: kz fixed, 16 bm values
    } else {
        bm = blockIdx.y; bn = blockIdx.x; kz = 0;
    }
    const int Kc = K / SPLITK;
    const int k_beg = kz * Kc;
    const int nIter = Kc / 32;

    const int t = threadIdx.x, w = t >> 6, lane = t & 63;
    const int wm = w >> 1, wn = w & 1;
    const int quad = lane >> 4, r16 = lane & 15;

    const int lr  = lane >> 2;
    const int lcg = (((lane & 3) ^ ((lr >> 1) & 3))) * 8;
    const u16* Ag0 = A  + (size_t)(bm * 128 + w * 32 + lr) * K + lcg + k_beg;
    const u16* Ag1 = Ag0 + (size_t)16 * K;
    const u16* Bg0 = BT + (size_t)(bn * TN + w * (TN / 4) + lr) * K + lcg + k_beg;
    const u16* Bg1 = Bg0 + (size_t)16 * K;
    const int aoff0 = (w * 32 + lr) * 32 + (lane & 3) * 8;
    const int aoff1 = aoff0 + 16 * 32;
    const int boff0 = (w * (TN / 4) + lr) * 32 + (lane & 3) * 8;
    const int boff1 = boff0 + 16 * 32;

    const int sw = ((r16 >> 1) & 3);
    floatx4 acc[4][NT] = {};

    gload16(Ag0, a_s[0] + aoff0);
    gload16(Ag1, a_s[0] + aoff1);
    gload16(Bg0, b_s[0] + boff0);
    if constexpr (NT == 4) gload16(Bg1, b_s[0] + boff1);

    for (int i = 0; i < nIter; i++) {
        const int cur = i & 1, nxt = cur ^ 1;
        __syncthreads();   // drains cur-tile loads (issued one compute phase ago)
        if (i + 1 < nIter) {
            int kc2 = (i + 1) * 32;
            gload16(Ag0 + kc2, a_s[nxt] + aoff0);
            gload16(Ag1 + kc2, a_s[nxt] + aoff1);
            gload16(Bg0 + kc2, b_s[nxt] + boff0);
            if constexpr (NT == 4) gload16(Bg1 + kc2, b_s[nxt] + boff1);
        }
        short8 af[4], bf[NT];
        #pragma unroll
        for (int mt = 0; mt < 4; mt++)
            af[mt] = *(const short8*)(a_s[cur] + (wm * 64 + mt * 16 + r16) * 32 + (quad ^ sw) * 8);
        #pragma unroll
        for (int nt = 0; nt < NT; nt++)
            bf[nt] = *(const short8*)(b_s[cur] + (wn * (TN / 2) + nt * 16 + r16) * 32 + (quad ^ sw) * 8);
        #pragma unroll
        for (int mt = 0; mt < 4; mt++)
            #pragma unroll
            for (int nt = 0; nt < NT; nt++)
                acc[mt][nt] = __builtin_amdgcn_mfma_f32_16x16x32_bf16(af[mt], bf[nt], acc[mt][nt], 0, 0, 0);
    }

    #pragma unroll
    for (int mt = 0; mt < 4; mt++)
      #pragma unroll
      for (int nt = 0; nt < NT; nt++)
        #pragma unroll
        for (int r = 0; r < 4; r++) {
            int row = bm * 128 + wm * 64 + mt * 16 + quad * 4 + r;
            int col = bn * TN + wn * (TN / 2) + nt * 16 + r16;
            size_t oi = (size_t)row * N + col;
            if (OUT == 3) {
                ((u16*)C)[(size_t)kz * M * N + oi] = f2b(acc[mt][nt][r]);
            } else {
                float v = acc[mt][nt][r] + ldrawf(bias, col, isb);
                if (GELU) v = gelu_f(v);
                if (RES == 1) v += ldrawf(resid, (size_t)row * N + col, isb);
                ((u16*)C)[oi] = f2b(v);
            }
        }
}

// ---------------- split-K reduce: out = x1b + b2 + sum_z part[z] ----------------
__global__ __launch_bounds__(256) void reduce_k(const u16* __restrict__ part,
                                                const u16* __restrict__ x1b,
                                                const void* __restrict__ b2,
                                                void* __restrict__ out,
                                                const void* xprobe) {
    bool isb = is_bf16_in((const u16*)xprobe);
    size_t i0 = ((size_t)blockIdx.x * 256 + threadIdx.x) * 4;
    ushort4 xv = *(const ushort4*)(x1b + i0);
    float r[4] = { b2f(xv.x), b2f(xv.y), b2f(xv.z), b2f(xv.w) };
    #pragma unroll
    for (int j = 0; j < 4; j++) r[j] += ldrawf(b2, (i0 + j) & (D_ - 1), isb);
    #pragma unroll
    for (int z = 0; z < 4; z++) {
        ushort4 pv = *(const ushort4*)(part + (size_t)z * M_ * D_ + i0);
        r[0] += b2f(pv.x); r[1] += b2f(pv.y); r[2] += b2f(pv.z); r[3] += b2f(pv.w);
    }
    if (isb) {
        ushort4 ov = { f2b(r[0]), f2b(r[1]), f2b(r[2]), f2b(r[3]) };
        *(ushort4*)((u16*)out + i0) = ov;
    } else {
        float4 ov = { r[0], r[1], r[2], r[3] };
        *(float4*)((float*)out + i0) = ov;
    }
}

// ---------------- repack V only: qkv v-cols -> Vt [pid][64][l'] ----------------
__global__ __launch_bounds__(256) void repack_v_k(const u16* __restrict__ qkv,
                                                  u16* __restrict__ Vt) {
    int pid = blockIdx.x;            // 0..63
    int lt  = blockIdx.y;            // 0..15
    int b = pid >> 5, p = (pid >> 4) & 1, h = pid & 15;
    int t = threadIdx.x;
    int srow = t >> 2;
    int scol = (t & 3) * 16;

    int lp = lt * 64 + srow;
    int l  = 2 * lp + p;
    const u16* src = qkv + ((size_t)b * L_ + l) * (3 * D_) + 2 * D_ + h * HD_;

    __shared__ u16 vt[64][72];
    *(int4*)(&vt[srow][scol])     = *(const int4*)(src + scol);
    *(int4*)(&vt[srow][scol + 8]) = *(const int4*)(src + scol + 8);
    __syncthreads();
    union { u16 s[16]; int4 v[2]; } tmp;
    #pragma unroll
    for (int jj = 0; jj < 16; jj++) tmp.s[jj] = vt[scol + jj][srow];
    u16* vdst = Vt + ((size_t)pid * HD_ + srow) * LP_ + lt * 64 + scol;
    *(int4*)(vdst)     = tmp.v[0];
    *(int4*)(vdst + 8) = tmp.v[1];
}

// ---------------- flash attention (parity-compressed), reg-prefetch K/V ----------------
#define FS 72
__global__ __launch_bounds__(256) void fattn_k(const u16* __restrict__ qkv,
                                               const u16* __restrict__ Vt,
                                               u16* __restrict__ o) {
    __shared__ __align__(16) u16 Qs[64 * FS];
    __shared__ __align__(16) u16 Ks[64 * FS];
    __shared__ __align__(16) u16 Vs[64 * FS];
    __shared__ __align__(16) u16 Ps[4][16 * FS];

    const int pid = blockIdx.x, qt = blockIdx.y;
    const int b = pid >> 5, p = (pid >> 4) & 1, h = pid & 15;
    const int t = threadIdx.x, w = t >> 6, lane = t & 63;
    const int quad = lane >> 4, r16 = lane & 15;
    const int q0 = qt * 64;

    const int srow = t >> 2;
    const int scol = (t & 3) * 16;

    const u16* qsrc = qkv + ((size_t)b * L_ + 2 * (q0 + srow) + p) * (3 * D_) + h * HD_;
    *(int4*)(Qs + srow * FS + scol)     = *(const int4*)(qsrc + scol);
    *(int4*)(Qs + srow * FS + scol + 8) = *(const int4*)(qsrc + scol + 8);
    __syncthreads();

    const short8 qf0 = *(const short8*)(Qs + (w * 16 + r16) * FS + quad * 8);
    const short8 qf1 = *(const short8*)(Qs + (w * 16 + r16) * FS + quad * 8 + 32);

    floatx4 oacc[4] = {};
    float mrow[4] = {-INFINITY, -INFINITY, -INFINITY, -INFINITY};
    float lrow[4] = {};

    const int kt0 = (qt >= 4) ? qt - 4 : 0;
    const int qrow_base = q0 + w * 16 + quad * 4;

    auto kaddr = [&](int kt) {
        return qkv + ((size_t)b * L_ + 2 * (kt * 64 + srow) + p) * (3 * D_) + D_ + h * HD_;
    };
    auto vaddr = [&](int kt) {
        return Vt + ((size_t)pid * HD_ + srow) * LP_ + kt * 64;
    };
    int4 kr0 = *(const int4*)(kaddr(kt0) + scol);
    int4 kr1 = *(const int4*)(kaddr(kt0) + scol + 8);
    int4 vr0 = *(const int4*)(vaddr(kt0) + scol);
    int4 vr1 = *(const int4*)(vaddr(kt0) + scol + 8);

    for (int kt = kt0; kt <= qt; ++kt) {
        __syncthreads();
        *(int4*)(Ks + srow * FS + scol)     = kr0;
        *(int4*)(Ks + srow * FS + scol + 8) = kr1;
        *(int4*)(Vs + srow * FS + scol)     = vr0;
        *(int4*)(Vs + srow * FS + scol + 8) = vr1;
        __syncthreads();
        if (kt < qt) {
            kr0 = *(const int4*)(kaddr(kt + 1) + scol);
            kr1 = *(const int4*)(kaddr(kt + 1) + scol + 8);
            vr0 = *(const int4*)(vaddr(kt + 1) + scol);
            vr1 = *(const int4*)(vaddr(kt + 1) + scol + 8);
        }

        floatx4 s4[4];
        #pragma unroll
        for (int nt = 0; nt < 4; nt++) {
            short8 kf0 = *(const short8*)(Ks + (nt * 16 + r16) * FS + quad * 8);
            short8 kf1 = *(const short8*)(Ks + (nt * 16 + r16) * FS + quad * 8 + 32);
            floatx4 z = {};
            z = __builtin_amdgcn_mfma_f32_16x16x32_bf16(qf0, kf0, z, 0, 0, 0);
            z = __builtin_amdgcn_mfma_f32_16x16x32_bf16(qf1, kf1, z, 0, 0, 0);
            s4[nt] = z;
        }

        float sv[4][4];
        #pragma unroll
        for (int nt = 0; nt < 4; nt++) {
            int kcol = kt * 64 + nt * 16 + r16;
            #pragma unroll
            for (int r = 0; r < 4; r++) {
                int kq = kcol - (qrow_base + r);
                bool valid = (kq <= 0) && (kq >= -WP_);
                sv[nt][r] = valid ? s4[nt][r] * 0.125f : -1e30f;
            }
        }

        float mx[4];
        #pragma unroll
        for (int r = 0; r < 4; r++)
            mx[r] = fmaxf(fmaxf(sv[0][r], sv[1][r]), fmaxf(sv[2][r], sv[3][r]));
        #pragma unroll
        for (int off = 8; off >= 1; off >>= 1)
            #pragma unroll
            for (int r = 0; r < 4; r++) mx[r] = fmaxf(mx[r], __shfl_xor(mx[r], off));

        float al[4];
        #pragma unroll
        for (int r = 0; r < 4; r++) {
            float mnew = fmaxf(mrow[r], mx[r]);
            al[r] = __expf(mrow[r] - mnew);
            mrow[r] = mnew;
        }

        float ps[4][4], rs[4] = {};
        #pragma unroll
        for (int nt = 0; nt < 4; nt++)
            #pragma unroll
            for (int r = 0; r < 4; r++) {
                float pv = __expf(sv[nt][r] - mrow[r]);
                ps[nt][r] = pv; rs[r] += pv;
            }
        #pragma unroll
        for (int off = 8; off >= 1; off >>= 1)
            #pragma unroll
            for (int r = 0; r < 4; r++) rs[r] += __shfl_xor(rs[r], off);
        #pragma unroll
        for (int r = 0; r < 4; r++) lrow[r] = lrow[r] * al[r] + rs[r];
        #pragma unroll
        for (int nt = 0; nt < 4; nt++)
            #pragma unroll
            for (int r = 0; r < 4; r++) oacc[nt][r] *= al[r];

        #pragma unroll
        for (int nt = 0; nt < 4; nt++)
            #pragma unroll
            for (int r = 0; r < 4; r++)
                Ps[w][(quad * 4 + r) * FS + nt * 16 + r16] = f2b(ps[nt][r]);
        short8 pf0 = *(const short8*)(&Ps[w][r16 * FS + quad * 8]);
        short8 pf1 = *(const short8*)(&Ps[w][r16 * FS + quad * 8 + 32]);

        #pragma unroll
        for (int nt = 0; nt < 4; nt++) {
            short8 vf0 = *(const short8*)(Vs + (nt * 16 + r16) * FS + quad * 8);
            short8 vf1 = *(const short8*)(Vs + (nt * 16 + r16) * FS + quad * 8 + 32);
            oacc[nt] = __builtin_amdgcn_mfma_f32_16x16x32_bf16(pf0, vf0, oacc[nt], 0, 0, 0);
            oacc[nt] = __builtin_amdgcn_mfma_f32_16x16x32_bf16(pf1, vf1, oacc[nt], 0, 0, 0);
        }
    }

    float inv[4];
    #pragma unroll
    for (int r = 0; r < 4; r++) inv[r] = 1.0f / lrow[r];
    #pragma unroll
    for (int nt = 0; nt < 4; nt++)
        #pragma unroll
        for (int r = 0; r < 4; r++) {
            int qp = qrow_base + r;
            int l  = 2 * qp + p;
            int d  = nt * 16 + r16;
            o[((size_t)b * L_ + l) * D_ + h * HD_ + d] = f2b(oacc[nt][r] * inv[r]);
        }
}

// ---------------- orchestration ----------------
extern "C" void kernel_launch(void* const* d_in, const int* in_sizes, int n_in,
                              void* d_out, int out_size, void* d_ws, size_t ws_size,
                              hipStream_t stream) {
    (void)in_sizes; (void)n_in; (void)out_size; (void)ws_size;
    const void* x     = d_in[0];
    const void* ln1_g = d_in[1];
    const void* ln1_b = d_in[2];
    const void* Wqkv  = d_in[3];
    const void* bqkv  = d_in[4];
    const void* Wout  = d_in[5];
    const void* bout  = d_in[6];
    const void* ln2_g = d_in[7];
    const void* ln2_b = d_in[8];
    const void* W1    = d_in[9];
    const void* b1    = d_in[10];
    const void* W2    = d_in[11];
    const void* b2    = d_in[12];

    char* ws = (char*)d_ws;
    const size_t MB = 1024 * 1024;
    u16*   wqkvT = (u16*)ws;                      // 6MB   [3D, D]
    u16*   qkv   = (u16*)(ws + 6  * MB);          // 24MB  [M, 3D]
    u16*   woutT = (u16*)(ws + 30 * MB);          // 2MB   [D, D]
    u16*   fbuf  = (u16*)ws;                      // 32MB  [M,4D] overlay (GEMM3+)
    u16*   w1T   = (u16*)(ws + 32 * MB);          // 8MB   [4D, D]
    u16*   w2T   = (u16*)(ws + 40 * MB);          // 8MB   [D, 4D]
    u16*   bufA  = (u16*)(ws + 48 * MB);          // 8MB   [M, D]
    u16*   x1b   = (u16*)(ws + 56 * MB);          // 8MB   [M, D] bf16 residual trunk
    u16*   Vt    = (u16*)(ws + 72 * MB);          // 8MB   [64][64][1024]
    u16*   part  = (u16*)(ws + 80 * MB);          // 32MB  4 x [M, D] bf16 split-K partials

    dim3 tb(256);

    // prep: 4 transposes (12288 blocks) + LN1 (4096 blocks), one launch
    prep_k<<<16384, tb, 0, stream>>>(Wqkv, Wout, W1, W2, wqkvT, woutT, w1T, w2T,
                                     x, ln1_g, ln1_b, bufA);

    // GEMM1: qkv = h @ Wqkv + bqkv    [4096 x 3072 x 1024]
    gemm128_k<4, 1, 0, 0, 1><<<dim3(3 * D_ / 128, M_ / 128), tb, 0, stream>>>(bufA, wqkvT, bqkv, nullptr, qkv, M_, 3 * D_, D_, x);

    repack_v_k<<<dim3(64, 16), tb, 0, stream>>>(qkv, Vt);
    fattn_k<<<dim3(64, 16), tb, 0, stream>>>(qkv, Vt, bufA);

    // GEMM2: x1b = o @ Wout + bout + x  [4096 x 1024 x 1024], bf16 trunk
    gemm128_k<2, 1, 1, 0, 1><<<dim3(D_ / 64, M_ / 128), tb, 0, stream>>>(bufA, woutT, bout, x, x1b, M_, D_, D_, x);

    // LN2: x1b -> h2 (bufA)
    ln2_k<<<M_, tb, 0, stream>>>(x1b, ln2_g, ln2_b, bufA, x);

    // GEMM3: f = gelu(h2 @ W1 + b1)   [4096 x 4096 x 1024]
    gemm128_k<4, 1, 0, 1, 1><<<dim3(4 * D_ / 128, M_ / 128), tb, 0, stream>>>(bufA, w1T, b1, nullptr, fbuf, M_, 4 * D_, D_, x);

    // GEMM4 split-K=4, XCD-swizzled 1D grid: part[z] = f @ W2 (K-chunk z)
    gemm128_k<2, 3, 0, 0, 4><<<2048, tb, 0, stream>>>(fbuf, w2T, nullptr, nullptr, part, M_, D_, 4 * D_, x);
    // reduce: out = x1b + b2 + sum(part)
    reduce_k<<<(M_ * D_) / 1024, tb, 0, stream>>>(part, x1b, b2, d_out, x);
}